// Round 11
// baseline (23354.222 us; speedup 1.0000x reference)
//
#include <hip/hip_runtime.h>
#include <cstdint>
#include <cstddef>

#define B_SZ 64
#define T_SZ 1536
#define C_SZ 256
#define H_SZ 512
#define G4H  2048
#define POLL_BUDGET 50000000

typedef __attribute__((ext_vector_type(8))) short short8;
typedef __attribute__((ext_vector_type(4))) float f32x4;

__device__ __forceinline__ unsigned short f2bf_rne(float f) {
    unsigned u = __float_as_uint(f);
    unsigned r = (u + 0x7FFF + ((u >> 16) & 1)) >> 16;
    return (unsigned short)r;
}
__device__ __forceinline__ float sigmoid_f(float x) {
    return 1.f / (1.f + __expf(-x));
}
__device__ __forceinline__ float tanh_f(float x) {
    return 1.f - 2.f / (__expf(2.f * x) + 1.f);
}

// ---------------------------------------------------------------------------
// Input GEMM (verified R2-R10). Output [tlen][B][4H].
// ---------------------------------------------------------------------------
template<int AMODE>
__global__ __launch_bounds__(256)
void gemm_gx(const float* __restrict__ A, const float* __restrict__ W,
             const float* __restrict__ bias1, const float* __restrict__ bias2,
             float* __restrict__ gx, int K, int astride_b, int t0g, int tlen)
{
    __shared__ float a_s[8][132];
    __shared__ float b_s[8][132];
    const int tb = blockIdx.x, nb = blockIdx.y, b = blockIdx.z;
    const int tloc = tb * 128;
    const int tglb = t0g + tloc;
    const int r0 = nb * 128;
    const float* Ab = A + (size_t)b * astride_b;
    const int tid = threadIdx.x;
    const int tx = tid & 15, ty = tid >> 4;
    float acc[8][8] = {};

    for (int k0 = 0; k0 < K; k0 += 8) {
        if (AMODE == 0) {
            const int row = tid >> 5;
            const int col = (tid & 31) << 2;
            const float4 v = *(const float4*)(Ab + (size_t)(k0 + row) * T_SZ + tglb + col);
            *(float4*)&a_s[row][col] = v;
        } else {
            const int row  = tid >> 1;
            const int half = (tid & 1) << 2;
            const float4 v = *(const float4*)(Ab + (size_t)(tglb + row) * H_SZ + k0 + half);
            a_s[half + 0][row] = v.x; a_s[half + 1][row] = v.y;
            a_s[half + 2][row] = v.z; a_s[half + 3][row] = v.w;
        }
        {
            const int row  = tid >> 1;
            const int half = (tid & 1) << 2;
            const float4 v = *(const float4*)(W + (size_t)(r0 + row) * K + k0 + half);
            b_s[half + 0][row] = v.x; b_s[half + 1][row] = v.y;
            b_s[half + 2][row] = v.z; b_s[half + 3][row] = v.w;
        }
        __syncthreads();
        #pragma unroll
        for (int kk = 0; kk < 8; ++kk) {
            float4 a0 = *(const float4*)&a_s[kk][tx * 8];
            float4 a1 = *(const float4*)&a_s[kk][tx * 8 + 4];
            float4 w0 = *(const float4*)&b_s[kk][ty * 8];
            float4 w1 = *(const float4*)&b_s[kk][ty * 8 + 4];
            float av[8] = {a0.x, a0.y, a0.z, a0.w, a1.x, a1.y, a1.z, a1.w};
            float wv[8] = {w0.x, w0.y, w0.z, w0.w, w1.x, w1.y, w1.z, w1.w};
            #pragma unroll
            for (int i = 0; i < 8; ++i)
                #pragma unroll
                for (int j = 0; j < 8; ++j)
                    acc[i][j] += wv[i] * av[j];
        }
        __syncthreads();
    }
    float bs[8];
    #pragma unroll
    for (int i = 0; i < 8; ++i)
        bs[i] = bias1[r0 + ty * 8 + i] + bias2[r0 + ty * 8 + i];
    #pragma unroll
    for (int j = 0; j < 8; ++j) {
        float* dst = gx + ((size_t)(tloc + tx * 8 + j) * B_SZ + b) * G4H + r0 + ty * 8;
        float4 o0 = {acc[0][j] + bs[0], acc[1][j] + bs[1], acc[2][j] + bs[2], acc[3][j] + bs[3]};
        float4 o1 = {acc[4][j] + bs[4], acc[5][j] + bs[5], acc[6][j] + bs[6], acc[7][j] + bs[7]};
        *(float4*)dst = o0; *(float4*)(dst + 4) = o1;
    }
}

// ---------------------------------------------------------------------------
__global__ void wsplit(const float* __restrict__ w,
                       unsigned short* __restrict__ hi,
                       unsigned short* __restrict__ lo, int n)
{
    const int i = blockIdx.x * 256 + threadIdx.x;
    if (i < n) {
        const float v = w[i];
        const unsigned short h = f2bf_rne(v);
        hi[i] = h;
        lo[i] = f2bf_rne(v - __uint_as_float(((unsigned)h) << 16));
    }
}

// ---------------------------------------------------------------------------
// MFMA LSTM scan v9: R9 core (verified: relaxed agent-atomic self-validating
// exchange, u32 = h_bf16<<16 | cbits, cbits = ((t>>1)&1)|2; W hi/lo in AGPRs,
// h bf16-only in LDS; sentinel poll) + TWO-WAY BATCH-GROUP INTERLEAVE:
// each WG serves groups 2p and 2p+1 with the SAME W registers, alternating
// phases A/B per timestep. Group A's publish->poll window now contains the
// whole of phase B (~1.4us of MFMA/update), hiding that much of the exchange
// latency. R10's XCD-local channel is abandoned (unverified memory model ->
// silent staleness); everything here uses the R4-R9-verified atomic medium.
// Grid = 32 WGs x 512 thr: WG (p = bid&1 -> groups {2p,2p+1}, w = bid>>1 ->
// units w*32..+31). LDS 64KB (2 groups x 2 parity x 16KB), 1 block/CU.
// ---------------------------------------------------------------------------
__global__ __launch_bounds__(512, 1)
void lstm_scan_mfma(const float* __restrict__ gx,            // [tlen][B][4H]
                    const unsigned short* __restrict__ Whi,  // [4H][H] bf16 bits
                    const unsigned short* __restrict__ Wlo,
                    float* __restrict__ h_out,               // [B][T][H]
                    unsigned int* hex,                       // [2][4][16][512] u32
                    float* __restrict__ c_state,             // [B][H]
                    int t0, int steps, int tlen)
{
    __shared__ __align__(16) char hHI[2][2][16384]; // [ph][pb][16 b][512 u]

    const int tid  = threadIdx.x;
    const int p    = blockIdx.x & 1;      // group pair
    const int w    = blockIdx.x >> 1;     // 0..15 unit slice
    const int wv   = tid >> 6;            // wave 0..7
    const int lane = tid & 63;
    const int m16  = lane & 15;           // batch col / A-tile row
    const int q    = lane >> 4;           // k-subgroup / unit-in-wave

    // --- W fragments (AGPR-resident): A-row r=m16 <-> (gate r&3, du r>>2)
    short8 whi[16], wlo[16];
    {
        const size_t rowbase =
            (size_t)((m16 & 3) * H_SZ + w * 32 + wv * 4 + (m16 >> 2)) * H_SZ + q * 8;
        #pragma unroll
        for (int kk = 0; kk < 16; ++kk) {
            whi[kk] = *(const short8*)(Whi + rowbase + kk * 32);
            wlo[kk] = *(const short8*)(Wlo + rowbase + kk * 32);
        }
    }

    // this lane's (batch, unit) per phase: C/D col=m16, row=q*4+pp <-> gate pp
    const int ug = w * 32 + wv * 4 + q;
    const int swz = (m16 & 7) << 4;
    long long polls = 0;

    float c_val[2], h_prev[2];
    float gxc[2][4];
    #pragma unroll
    for (int ph = 0; ph < 2; ++ph) {
        const int bg = (2 * p + ph) * 16 + m16;
        c_val[ph]  = (t0 > 0) ? c_state[(size_t)bg * H_SZ + ug] : 0.f;
        h_prev[ph] = 0.f;
        const float* gxp = gx + (size_t)bg * G4H + ug;
        #pragma unroll
        for (int pp = 0; pp < 4; ++pp) gxc[ph][pp] = gxp[pp * H_SZ];
    }

    for (int tt = 0; tt < steps; ++tt) {
        const int t  = t0 + tt;
        const int pb = tt & 1;

        #pragma unroll
        for (int ph = 0; ph < 2; ++ph) {
            const int g  = 2 * p + ph;
            const int bg = g * 16 + m16;
            char* dHI = hHI[ph][pb];
            const float* gxp = gx + (size_t)bg * G4H + ug;

            // ---- staging loads + sentinel poll (group g)
            unsigned vv[16];
            if (t > 0) {
                const unsigned cexp = ((unsigned)((t - 1) >> 1) & 1u) | 2u;
                const unsigned int* src =
                    hex + ((size_t)((t - 1) & 1) * 4 + g) * 8192 + tid;
                #pragma unroll
                for (int m = 0; m < 16; ++m)
                    vv[m] = __hip_atomic_load(src + m * 512, __ATOMIC_RELAXED,
                                              __HIP_MEMORY_SCOPE_AGENT);
                for (;;) {
                    while ((vv[0] & 3u) != cexp) {
                        if (++polls > POLL_BUDGET) break;
                        vv[0] = __hip_atomic_load(src, __ATOMIC_RELAXED,
                                                  __HIP_MEMORY_SCOPE_AGENT);
                    }
                    bool ok = true;
                    #pragma unroll
                    for (int m = 1; m < 16; ++m)
                        if ((vv[m] & 3u) != cexp) {
                            vv[m] = __hip_atomic_load(src + m * 512, __ATOMIC_RELAXED,
                                                      __HIP_MEMORY_SCOPE_AGENT);
                            ok = false;
                        }
                    if (ok || polls > POLL_BUDGET) break;
                }
                asm volatile("" ::: "memory");  // pin off-path ops below poll
            }

            // ---- off-critical-path: h_out(t-1) store, gx(t+1) prefetch
            if (tt > 0)
                h_out[((size_t)bg * T_SZ + (t - 1)) * H_SZ + ug] = h_prev[ph];
            float gxn[4] = {0.f, 0.f, 0.f, 0.f};
            if (tt + 1 < steps) {
                const float* gn = gxp + (size_t)(tt + 1) * (B_SZ * G4H);
                #pragma unroll
                for (int pp = 0; pp < 4; ++pp) gxn[pp] = gn[pp * H_SZ];
            }

            // ---- stage into swizzled LDS buf[ph][pb] (hi only)
            if (t == 0) {
                const float4 z = {0.f, 0.f, 0.f, 0.f};
                *(float4*)(dHI + tid * 16)        = z;
                *(float4*)(dHI + tid * 16 + 8192) = z;
            } else {
                #pragma unroll
                for (int m = 0; m < 16; ++m) {
                    const int off = ((m << 10) + 2 * tid) ^ ((m & 7) << 4);
                    *(unsigned short*)(dHI + off) = (unsigned short)(vv[m] >> 16);
                }
            }
            __syncthreads();   // one barrier per phase

            // ---- 2-product MFMA (W hi/lo compensated, h bf16), K=512
            f32x4 a0 = {0.f, 0.f, 0.f, 0.f};
            f32x4 a2 = {0.f, 0.f, 0.f, 0.f};
            const char* hb = dHI + (m16 << 10);
            #pragma unroll
            for (int kk = 0; kk < 16; ++kk) {
                const int off = (kk * 64 + q * 16) ^ swz;
                const short8 hh = *(const short8*)(hb + off);
                a0 = __builtin_amdgcn_mfma_f32_16x16x32_bf16(whi[kk], hh, a0, 0, 0, 0);
                a2 = __builtin_amdgcn_mfma_f32_16x16x32_bf16(wlo[kk], hh, a2, 0, 0, 0);
            }

            // ---- in-lane update + publish (group g)
            {
                const float gi = a0[0] + a2[0] + gxc[ph][0];
                const float gf = a0[1] + a2[1] + gxc[ph][1];
                const float gc = a0[2] + a2[2] + gxc[ph][2];
                const float go = a0[3] + a2[3] + gxc[ph][3];
                const float si = sigmoid_f(gi);
                const float sf = sigmoid_f(gf);
                const float tc = tanh_f(gc);
                const float so = sigmoid_f(go);
                c_val[ph] = sf * c_val[ph] + si * tc;
                const float h = so * tanh_f(c_val[ph]);
                const unsigned hb16 = f2bf_rne(h);
                const unsigned cb   = ((unsigned)(t >> 1) & 1u) | 2u;
                __hip_atomic_store(hex + ((size_t)(t & 1) * 4 + g) * 8192
                                       + m16 * 512 + ug,
                                   (hb16 << 16) | cb,
                                   __ATOMIC_RELAXED, __HIP_MEMORY_SCOPE_AGENT);
                h_prev[ph] = h;
            }
            #pragma unroll
            for (int pp = 0; pp < 4; ++pp) gxc[ph][pp] = gxn[pp];
        }
    }
    // deferred last h_out store + cross-chunk c carry (both groups)
    #pragma unroll
    for (int ph = 0; ph < 2; ++ph) {
        const int bg = (2 * p + ph) * 16 + m16;
        h_out[((size_t)bg * T_SZ + (t0 + steps - 1)) * H_SZ + ug] = h_prev[ph];
        if (t0 + steps < T_SZ)
            c_state[(size_t)bg * H_SZ + ug] = c_val[ph];
    }
}

// Beacon: surfaces ws_size (MiB) through the absmax error if ws is too small.
__global__ void debug_ws_beacon(float* out, float v)
{
    if (threadIdx.x == 0 && blockIdx.x == 0) out[0] = v;
}

// ---------------------------------------------------------------------------
extern "C" void kernel_launch(void* const* d_in, const int* in_sizes, int n_in,
                              void* d_out, int out_size, void* d_ws, size_t ws_size,
                              hipStream_t stream)
{
    const float* x    = (const float*)d_in[0];
    const float* Wih0 = (const float*)d_in[1];
    const float* Whh0 = (const float*)d_in[2];
    const float* bih0 = (const float*)d_in[3];
    const float* bhh0 = (const float*)d_in[4];
    const float* Wih1 = (const float*)d_in[5];
    const float* Whh1 = (const float*)d_in[6];
    const float* bih1 = (const float*)d_in[7];
    const float* bhh1 = (const float*)d_in[8];
    float* out = (float*)d_out;

    const size_t hexB  = (size_t)2 * 4 * 16 * H_SZ * 4;   // 256 KiB
    const size_t cstB  = (size_t)B_SZ * H_SZ * 4;         // 128 KiB
    const size_t wB    = (size_t)G4H * H_SZ * 2;          // 2 MiB per matrix
    const size_t fixed = hexB + cstB + 4 * wB;

    static const int opts[] = {1536, 768, 512, 384, 256, 128};
    int T_CHUNK = 0;
    for (int i = 0; i < 6; ++i) {
        const size_t need = (size_t)B_SZ * G4H * opts[i] * 4 + fixed;
        if (need <= ws_size) { T_CHUNK = opts[i]; break; }
    }
    if (T_CHUNK == 0) {
        debug_ws_beacon<<<1, 1, 0, stream>>>(out, (float)(ws_size >> 20));
        return;
    }

    char* ws = (char*)d_ws;
    const size_t gxB = (size_t)B_SZ * G4H * T_CHUNK * 4;
    float*          gx      = (float*)ws;
    unsigned int*   hex     = (unsigned int*)(ws + gxB);
    float*          c_state = (float*)(ws + gxB + hexB);
    unsigned short* whi0    = (unsigned short*)(ws + gxB + hexB + cstB);
    unsigned short* wlo0    = whi0 + G4H * H_SZ;
    unsigned short* whi1    = wlo0 + G4H * H_SZ;
    unsigned short* wlo1    = whi1 + G4H * H_SZ;

    const int nW = G4H * H_SZ;
    wsplit<<<(nW + 255) / 256, 256, 0, stream>>>(Whh0, whi0, wlo0, nW);
    wsplit<<<(nW + 255) / 256, 256, 0, stream>>>(Whh1, whi1, wlo1, nW);

    const dim3 ggrid(T_CHUNK / 128, G4H / 128, B_SZ);

    // layer 0
    hipMemsetAsync(hex, 0, hexB, stream);   // cbits bit1=0 -> never valid
    for (int t0 = 0; t0 < T_SZ; t0 += T_CHUNK) {
        gemm_gx<0><<<ggrid, 256, 0, stream>>>(x, Wih0, bih0, bhh0, gx, C_SZ,
                                              C_SZ * T_SZ, t0, T_CHUNK);
        lstm_scan_mfma<<<32, 512, 0, stream>>>(gx, whi0, wlo0, out, hex,
                                               c_state, t0, T_CHUNK, T_CHUNK);
    }
    // layer 1
    hipMemsetAsync(hex, 0, hexB, stream);   // kill layer-0 cbits
    for (int t0 = 0; t0 < T_SZ; t0 += T_CHUNK) {
        gemm_gx<1><<<ggrid, 256, 0, stream>>>(out, Wih1, bih1, bhh1, gx, H_SZ,
                                              T_SZ * H_SZ, t0, T_CHUNK);
        lstm_scan_mfma<<<32, 512, 0, stream>>>(gx, whi1, wlo1, out, hex,
                                               c_state, t0, T_CHUNK, T_CHUNK);
    }
}

// Round 12
// 20597.633 us; speedup vs baseline: 1.1338x; 1.1338x over previous
//
#include <hip/hip_runtime.h>
#include <cstdint>
#include <cstddef>

#define B_SZ 64
#define T_SZ 1536
#define C_SZ 256
#define H_SZ 512
#define G4H  2048
#define POLL_BUDGET 50000000

typedef __attribute__((ext_vector_type(8))) short short8;
typedef __attribute__((ext_vector_type(4))) float f32x4;

__device__ __forceinline__ unsigned short f2bf_rne(float f) {
    unsigned u = __float_as_uint(f);
    unsigned r = (u + 0x7FFF + ((u >> 16) & 1)) >> 16;
    return (unsigned short)r;
}
__device__ __forceinline__ float sigmoid_f(float x) {
    return 1.f / (1.f + __expf(-x));
}
__device__ __forceinline__ float tanh_f(float x) {
    return 1.f - 2.f / (__expf(2.f * x) + 1.f);
}

// ---------------------------------------------------------------------------
// Input GEMM (verified R2-R11). Output [tlen][B][4H].
// ---------------------------------------------------------------------------
template<int AMODE>
__global__ __launch_bounds__(256)
void gemm_gx(const float* __restrict__ A, const float* __restrict__ W,
             const float* __restrict__ bias1, const float* __restrict__ bias2,
             float* __restrict__ gx, int K, int astride_b, int t0g, int tlen)
{
    __shared__ float a_s[8][132];
    __shared__ float b_s[8][132];
    const int tb = blockIdx.x, nb = blockIdx.y, b = blockIdx.z;
    const int tloc = tb * 128;
    const int tglb = t0g + tloc;
    const int r0 = nb * 128;
    const float* Ab = A + (size_t)b * astride_b;
    const int tid = threadIdx.x;
    const int tx = tid & 15, ty = tid >> 4;
    float acc[8][8] = {};

    for (int k0 = 0; k0 < K; k0 += 8) {
        if (AMODE == 0) {
            const int row = tid >> 5;
            const int col = (tid & 31) << 2;
            const float4 v = *(const float4*)(Ab + (size_t)(k0 + row) * T_SZ + tglb + col);
            *(float4*)&a_s[row][col] = v;
        } else {
            const int row  = tid >> 1;
            const int half = (tid & 1) << 2;
            const float4 v = *(const float4*)(Ab + (size_t)(tglb + row) * H_SZ + k0 + half);
            a_s[half + 0][row] = v.x; a_s[half + 1][row] = v.y;
            a_s[half + 2][row] = v.z; a_s[half + 3][row] = v.w;
        }
        {
            const int row  = tid >> 1;
            const int half = (tid & 1) << 2;
            const float4 v = *(const float4*)(W + (size_t)(r0 + row) * K + k0 + half);
            b_s[half + 0][row] = v.x; b_s[half + 1][row] = v.y;
            b_s[half + 2][row] = v.z; b_s[half + 3][row] = v.w;
        }
        __syncthreads();
        #pragma unroll
        for (int kk = 0; kk < 8; ++kk) {
            float4 a0 = *(const float4*)&a_s[kk][tx * 8];
            float4 a1 = *(const float4*)&a_s[kk][tx * 8 + 4];
            float4 w0 = *(const float4*)&b_s[kk][ty * 8];
            float4 w1 = *(const float4*)&b_s[kk][ty * 8 + 4];
            float av[8] = {a0.x, a0.y, a0.z, a0.w, a1.x, a1.y, a1.z, a1.w};
            float wv[8] = {w0.x, w0.y, w0.z, w0.w, w1.x, w1.y, w1.z, w1.w};
            #pragma unroll
            for (int i = 0; i < 8; ++i)
                #pragma unroll
                for (int j = 0; j < 8; ++j)
                    acc[i][j] += wv[i] * av[j];
        }
        __syncthreads();
    }
    float bs[8];
    #pragma unroll
    for (int i = 0; i < 8; ++i)
        bs[i] = bias1[r0 + ty * 8 + i] + bias2[r0 + ty * 8 + i];
    #pragma unroll
    for (int j = 0; j < 8; ++j) {
        float* dst = gx + ((size_t)(tloc + tx * 8 + j) * B_SZ + b) * G4H + r0 + ty * 8;
        float4 o0 = {acc[0][j] + bs[0], acc[1][j] + bs[1], acc[2][j] + bs[2], acc[3][j] + bs[3]};
        float4 o1 = {acc[4][j] + bs[4], acc[5][j] + bs[5], acc[6][j] + bs[6], acc[7][j] + bs[7]};
        *(float4*)dst = o0; *(float4*)(dst + 4) = o1;
    }
}

// ---------------------------------------------------------------------------
__global__ void wsplit(const float* __restrict__ w,
                       unsigned short* __restrict__ hi,
                       unsigned short* __restrict__ lo, int n)
{
    const int i = blockIdx.x * 256 + threadIdx.x;
    if (i < n) {
        const float v = w[i];
        const unsigned short h = f2bf_rne(v);
        hi[i] = h;
        lo[i] = f2bf_rne(v - __uint_as_float(((unsigned)h) << 16));
    }
}

// ---------------------------------------------------------------------------
// MFMA LSTM scan v10: R9 verified core + 8-DEEP RING EXCHANGE, EXACT TAGS.
// value u32 = h_bf16 << 16 | (t+1): the low 16 bits are an exact step tag
// (1..1536; memset-0 never valid; no generation ambiguity at any depth).
// Ring slot = t & 7 (hex = [8][4][16][512] u32, 1 MB). Fast WGs run up to
// ~8 steps ahead; the ensemble advances at the MEAN per-WG rate instead of
// the per-step MAX across 64 WGs (the R6-R11 lockstep-jitter floor).
// Overwrite safety: publishing t implies all WGs published t-1 (consumption
// chain), so tag t-8 is dead before slot reuse; deadlock-free.
// Poll: R6-style parallel all-16 (sentinel reverted — R9's only other delta).
// Grid = 64 WGs x 512 thr: WG (grp=bid&3: 16 batches, w=bid>>2: 32 units).
// ---------------------------------------------------------------------------
__global__ __launch_bounds__(512, 2)
void lstm_scan_mfma(const float* __restrict__ gx,            // [tlen][B][4H]
                    const unsigned short* __restrict__ Whi,  // [4H][H] bf16 bits
                    const unsigned short* __restrict__ Wlo,
                    float* __restrict__ h_out,               // [B][T][H]
                    unsigned int* hex,                       // [8][4][16][512] u32
                    float* __restrict__ c_state,             // [B][H]
                    int t0, int steps, int tlen)
{
    __shared__ __align__(16) char hHI[2][16384];  // [pb][16 b][512 u] bf16, swizzled

    const int tid  = threadIdx.x;
    const int grp  = blockIdx.x & 3;
    const int w    = blockIdx.x >> 2;     // 0..15
    const int wv   = tid >> 6;            // wave 0..7
    const int lane = tid & 63;
    const int m16  = lane & 15;           // batch col / A-tile row
    const int q    = lane >> 4;           // k-subgroup / unit-in-wave

    // --- W fragments (AGPR-resident): A-row r=m16 <-> (gate r&3, du r>>2)
    short8 whi[16], wlo[16];
    {
        const size_t rowbase =
            (size_t)((m16 & 3) * H_SZ + w * 32 + wv * 4 + (m16 >> 2)) * H_SZ + q * 8;
        #pragma unroll
        for (int kk = 0; kk < 16; ++kk) {
            whi[kk] = *(const short8*)(Whi + rowbase + kk * 32);
            wlo[kk] = *(const short8*)(Wlo + rowbase + kk * 32);
        }
    }

    // this lane's (batch, unit): C/D col=m16, row=q*4+p <-> gate p, unit q
    const int ug = w * 32 + wv * 4 + q;
    const int bg = grp * 16 + m16;
    float c_val = (t0 > 0) ? c_state[(size_t)bg * H_SZ + ug] : 0.f;
    float h_prev = 0.f;

    const float* gxp = gx + (size_t)bg * G4H + ug;   // + tt*B*4H + p*512
    const int swz = (m16 & 7) << 4;
    long long polls = 0;

    float gxc[4];
    #pragma unroll
    for (int p = 0; p < 4; ++p) gxc[p] = gxp[p * H_SZ];

    for (int tt = 0; tt < steps; ++tt) {
        const int t  = t0 + tt;
        const int pb = tt & 1;
        char* dHI = hHI[pb];

        // ---- staging loads + parallel tag poll (exact tag = t)
        unsigned v[16];
        if (t > 0) {
            const unsigned cexp = (unsigned)t;   // producer stored (t-1)+1
            const unsigned int* src =
                hex + ((size_t)((t - 1) & 7) * 4 + grp) * 8192 + tid;
            #pragma unroll
            for (int m = 0; m < 16; ++m)
                v[m] = __hip_atomic_load(src + m * 512, __ATOMIC_RELAXED,
                                         __HIP_MEMORY_SCOPE_AGENT);
            for (;;) {
                bool ok = true;
                #pragma unroll
                for (int m = 0; m < 16; ++m)
                    if ((v[m] & 0xFFFFu) != cexp) {
                        v[m] = __hip_atomic_load(src + m * 512, __ATOMIC_RELAXED,
                                                 __HIP_MEMORY_SCOPE_AGENT);
                        ok = false;
                    }
                if (ok) break;
                if (++polls > POLL_BUDGET) break;   // hang safety valve
            }
            asm volatile("" ::: "memory");   // pin off-path ops below the poll
        }

        // ---- off-critical-path: h_out(t-1) store, gx(t+1) prefetch
        if (tt > 0)
            h_out[((size_t)bg * T_SZ + (t - 1)) * H_SZ + ug] = h_prev;
        float gxn[4] = {0.f, 0.f, 0.f, 0.f};
        if (tt + 1 < steps) {
            const float* gn = gxp + (size_t)(tt + 1) * (B_SZ * G4H);
            #pragma unroll
            for (int p = 0; p < 4; ++p) gxn[p] = gn[p * H_SZ];
        }

        // ---- stage into swizzled LDS buf[pb] (hi bf16 only)
        if (t == 0) {
            const float4 z = {0.f, 0.f, 0.f, 0.f};
            *(float4*)(dHI + tid * 16)        = z;
            *(float4*)(dHI + tid * 16 + 8192) = z;
        } else {
            #pragma unroll
            for (int m = 0; m < 16; ++m) {
                const int off = ((m << 10) + 2 * tid) ^ ((m & 7) << 4);
                *(unsigned short*)(dHI + off) = (unsigned short)(v[m] >> 16);
            }
        }
        __syncthreads();   // the ONLY barrier per step

        // ---- 2-product MFMA (W hi/lo compensated, h bf16), full K=512
        f32x4 a0 = {0.f, 0.f, 0.f, 0.f};
        f32x4 a2 = {0.f, 0.f, 0.f, 0.f};
        const char* hb = dHI + (m16 << 10);
        #pragma unroll
        for (int kk = 0; kk < 16; ++kk) {
            const int off = (kk * 64 + q * 16) ^ swz;
            const short8 hh = *(const short8*)(hb + off);
            a0 = __builtin_amdgcn_mfma_f32_16x16x32_bf16(whi[kk], hh, a0, 0, 0, 0);
            a2 = __builtin_amdgcn_mfma_f32_16x16x32_bf16(wlo[kk], hh, a2, 0, 0, 0);
        }

        // ---- in-lane update + publish into ring slot t&7
        {
            const float gi = a0[0] + a2[0] + gxc[0];
            const float gf = a0[1] + a2[1] + gxc[1];
            const float gc = a0[2] + a2[2] + gxc[2];
            const float go = a0[3] + a2[3] + gxc[3];
            const float si = sigmoid_f(gi);
            const float sf = sigmoid_f(gf);
            const float tc = tanh_f(gc);
            const float so = sigmoid_f(go);
            c_val = sf * c_val + si * tc;
            const float h = so * tanh_f(c_val);
            const unsigned hb16 = f2bf_rne(h);
            __hip_atomic_store(hex + ((size_t)(t & 7) * 4 + grp) * 8192
                                   + m16 * 512 + ug,
                               (hb16 << 16) | (unsigned)(t + 1),
                               __ATOMIC_RELAXED, __HIP_MEMORY_SCOPE_AGENT);
            h_prev = h;
        }
        #pragma unroll
        for (int p = 0; p < 4; ++p) gxc[p] = gxn[p];
    }
    // deferred last h_out store + cross-chunk c carry
    h_out[((size_t)bg * T_SZ + (t0 + steps - 1)) * H_SZ + ug] = h_prev;
    if (t0 + steps < T_SZ)
        c_state[(size_t)bg * H_SZ + ug] = c_val;
}

// Beacon: surfaces ws_size (MiB) through the absmax error if ws is too small.
__global__ void debug_ws_beacon(float* out, float v)
{
    if (threadIdx.x == 0 && blockIdx.x == 0) out[0] = v;
}

// ---------------------------------------------------------------------------
extern "C" void kernel_launch(void* const* d_in, const int* in_sizes, int n_in,
                              void* d_out, int out_size, void* d_ws, size_t ws_size,
                              hipStream_t stream)
{
    const float* x    = (const float*)d_in[0];
    const float* Wih0 = (const float*)d_in[1];
    const float* Whh0 = (const float*)d_in[2];
    const float* bih0 = (const float*)d_in[3];
    const float* bhh0 = (const float*)d_in[4];
    const float* Wih1 = (const float*)d_in[5];
    const float* Whh1 = (const float*)d_in[6];
    const float* bih1 = (const float*)d_in[7];
    const float* bhh1 = (const float*)d_in[8];
    float* out = (float*)d_out;

    const size_t hexB  = (size_t)8 * 4 * 16 * H_SZ * 4;   // 1 MiB ring
    const size_t cstB  = (size_t)B_SZ * H_SZ * 4;         // 128 KiB
    const size_t wB    = (size_t)G4H * H_SZ * 2;          // 2 MiB per matrix
    const size_t fixed = hexB + cstB + 4 * wB;

    static const int opts[] = {1536, 768, 512, 384, 256, 128};
    int T_CHUNK = 0;
    for (int i = 0; i < 6; ++i) {
        const size_t need = (size_t)B_SZ * G4H * opts[i] * 4 + fixed;
        if (need <= ws_size) { T_CHUNK = opts[i]; break; }
    }
    if (T_CHUNK == 0) {
        debug_ws_beacon<<<1, 1, 0, stream>>>(out, (float)(ws_size >> 20));
        return;
    }

    char* ws = (char*)d_ws;
    const size_t gxB = (size_t)B_SZ * G4H * T_CHUNK * 4;
    float*          gx      = (float*)ws;
    unsigned int*   hex     = (unsigned int*)(ws + gxB);
    float*          c_state = (float*)(ws + gxB + hexB);
    unsigned short* whi0    = (unsigned short*)(ws + gxB + hexB + cstB);
    unsigned short* wlo0    = whi0 + G4H * H_SZ;
    unsigned short* whi1    = wlo0 + G4H * H_SZ;
    unsigned short* wlo1    = whi1 + G4H * H_SZ;

    const int nW = G4H * H_SZ;
    wsplit<<<(nW + 255) / 256, 256, 0, stream>>>(Whh0, whi0, wlo0, nW);
    wsplit<<<(nW + 255) / 256, 256, 0, stream>>>(Whh1, whi1, wlo1, nW);

    const dim3 ggrid(T_CHUNK / 128, G4H / 128, B_SZ);

    // layer 0
    hipMemsetAsync(hex, 0, hexB, stream);   // tag 0 never valid
    for (int t0 = 0; t0 < T_SZ; t0 += T_CHUNK) {
        gemm_gx<0><<<ggrid, 256, 0, stream>>>(x, Wih0, bih0, bhh0, gx, C_SZ,
                                              C_SZ * T_SZ, t0, T_CHUNK);
        lstm_scan_mfma<<<64, 512, 0, stream>>>(gx, whi0, wlo0, out, hex,
                                               c_state, t0, T_CHUNK, T_CHUNK);
    }
    // layer 1
    hipMemsetAsync(hex, 0, hexB, stream);   // kill layer-0 tags
    for (int t0 = 0; t0 < T_SZ; t0 += T_CHUNK) {
        gemm_gx<1><<<ggrid, 256, 0, stream>>>(out, Wih1, bih1, bhh1, gx, H_SZ,
                                              T_SZ * H_SZ, t0, T_CHUNK);
        lstm_scan_mfma<<<64, 512, 0, stream>>>(gx, whi1, wlo1, out, hex,
                                               c_state, t0, T_CHUNK, T_CHUNK);
    }
}

// Round 13
// 15181.421 us; speedup vs baseline: 1.5383x; 1.3568x over previous
//
#include <hip/hip_runtime.h>
#include <cstdint>
#include <cstddef>

#define B_SZ 64
#define T_SZ 1536
#define C_SZ 256
#define H_SZ 512
#define G4H  2048
#define POLL_BUDGET 5000000

typedef __attribute__((ext_vector_type(8))) short short8;
typedef __attribute__((ext_vector_type(4))) float f32x4;

__device__ __forceinline__ unsigned short f2bf_rne(float f) {
    unsigned u = __float_as_uint(f);
    unsigned r = (u + 0x7FFF + ((u >> 16) & 1)) >> 16;
    return (unsigned short)r;
}
__device__ __forceinline__ float sigmoid_f(float x) {
    return 1.f / (1.f + __expf(-x));
}
__device__ __forceinline__ float tanh_f(float x) {
    return 1.f - 2.f / (__expf(2.f * x) + 1.f);
}

// ---------------------------------------------------------------------------
// Input GEMM for layer 0 only (verified R2-R12). Output [tlen][B][4H].
// ---------------------------------------------------------------------------
template<int AMODE>
__global__ __launch_bounds__(256)
void gemm_gx(const float* __restrict__ A, const float* __restrict__ W,
             const float* __restrict__ bias1, const float* __restrict__ bias2,
             float* __restrict__ gx, int K, int astride_b, int t0g, int tlen)
{
    __shared__ float a_s[8][132];
    __shared__ float b_s[8][132];
    const int tb = blockIdx.x, nb = blockIdx.y, b = blockIdx.z;
    const int tloc = tb * 128;
    const int tglb = t0g + tloc;
    const int r0 = nb * 128;
    const float* Ab = A + (size_t)b * astride_b;
    const int tid = threadIdx.x;
    const int tx = tid & 15, ty = tid >> 4;
    float acc[8][8] = {};

    for (int k0 = 0; k0 < K; k0 += 8) {
        if (AMODE == 0) {
            const int row = tid >> 5;
            const int col = (tid & 31) << 2;
            const float4 v = *(const float4*)(Ab + (size_t)(k0 + row) * T_SZ + tglb + col);
            *(float4*)&a_s[row][col] = v;
        } else {
            const int row  = tid >> 1;
            const int half = (tid & 1) << 2;
            const float4 v = *(const float4*)(Ab + (size_t)(tglb + row) * H_SZ + k0 + half);
            a_s[half + 0][row] = v.x; a_s[half + 1][row] = v.y;
            a_s[half + 2][row] = v.z; a_s[half + 3][row] = v.w;
        }
        {
            const int row  = tid >> 1;
            const int half = (tid & 1) << 2;
            const float4 v = *(const float4*)(W + (size_t)(r0 + row) * K + k0 + half);
            b_s[half + 0][row] = v.x; b_s[half + 1][row] = v.y;
            b_s[half + 2][row] = v.z; b_s[half + 3][row] = v.w;
        }
        __syncthreads();
        #pragma unroll
        for (int kk = 0; kk < 8; ++kk) {
            float4 a0 = *(const float4*)&a_s[kk][tx * 8];
            float4 a1 = *(const float4*)&a_s[kk][tx * 8 + 4];
            float4 w0 = *(const float4*)&b_s[kk][ty * 8];
            float4 w1 = *(const float4*)&b_s[kk][ty * 8 + 4];
            float av[8] = {a0.x, a0.y, a0.z, a0.w, a1.x, a1.y, a1.z, a1.w};
            float wv[8] = {w0.x, w0.y, w0.z, w0.w, w1.x, w1.y, w1.z, w1.w};
            #pragma unroll
            for (int i = 0; i < 8; ++i)
                #pragma unroll
                for (int j = 0; j < 8; ++j)
                    acc[i][j] += wv[i] * av[j];
        }
        __syncthreads();
    }
    float bs[8];
    #pragma unroll
    for (int i = 0; i < 8; ++i)
        bs[i] = bias1[r0 + ty * 8 + i] + bias2[r0 + ty * 8 + i];
    #pragma unroll
    for (int j = 0; j < 8; ++j) {
        float* dst = gx + ((size_t)(tloc + tx * 8 + j) * B_SZ + b) * G4H + r0 + ty * 8;
        float4 o0 = {acc[0][j] + bs[0], acc[1][j] + bs[1], acc[2][j] + bs[2], acc[3][j] + bs[3]};
        float4 o1 = {acc[4][j] + bs[4], acc[5][j] + bs[5], acc[6][j] + bs[6], acc[7][j] + bs[7]};
        *(float4*)dst = o0; *(float4*)(dst + 4) = o1;
    }
}

// ---------------------------------------------------------------------------
__global__ void wsplit(const float* __restrict__ w,
                       unsigned short* __restrict__ hi,
                       unsigned short* __restrict__ lo, int n)
{
    const int i = blockIdx.x * 256 + threadIdx.x;
    if (i < n) {
        const float v = w[i];
        const unsigned short h = f2bf_rne(v);
        hi[i] = h;
        lo[i] = f2bf_rne(v - __uint_as_float(((unsigned)h) << 16));
    }
}

// ---------------------------------------------------------------------------
// FUSED two-layer LSTM scan (v11). 256 WGs x 256 thr, 1 WG/CU (exactly 256
// CUs). role = bid>>7: 0 = layer 0 (consumes gx0, publishes h0 ring);
// 1 = layer 1 (consumes h0 ring + its own h1 ring, computes gates1 =
// Wih1.h0(t) + Whh1.h1(t-1) + bias ON THE FLY via MFMA, writes h_out).
// Both layers pipeline-flow concurrently: total steps = T, not 2T; no gx1
// buffer, no gemm<1>, no h0 HBM round trip.
// Exchange = R12-verified 8-deep ring, exact tags (u32 = h_bf16<<16 | t+1;
// memset-0 never valid), relaxed agent atomics. W hi/lo AGPR-resident (role1:
// Whh1 AND Wih1 hi/lo = 256 regs; 256-thr WGs -> 1 wave/SIMD -> 512-reg
// budget). h travels bf16; W fully compensated.
// h0-ring overwrite guard: layer-1 WGs are mutually +-1-step locked, so WG
// w==0 publishing prog[grp]=t+1 after its poll implies all layer-1 WGs
// consumed h0(t-1); layer-0 publishing t waits prog >= t-6 (slot depth 8).
// Deadlock-free: h0 flow one-directional, all waits point backward in t.
// ---------------------------------------------------------------------------
__global__ __launch_bounds__(256, 1)
void lstm_fused(const float* __restrict__ gx,                 // [tlen][B][4H]
                const unsigned short* __restrict__ w0hi,      // Whh0 [4H][H]
                const unsigned short* __restrict__ w0lo,
                const unsigned short* __restrict__ w1ahi,     // Whh1
                const unsigned short* __restrict__ w1alo,
                const unsigned short* __restrict__ w1bhi,     // Wih1
                const unsigned short* __restrict__ w1blo,
                const float* __restrict__ bih1,
                const float* __restrict__ bhh1,
                float* __restrict__ h_out,                    // [B][T][H]
                unsigned int* hex0,                           // [8][4][16][512]
                unsigned int* hex1,                           // [8][4][16][512]
                float* __restrict__ c_state,                  // [2][B][H]
                unsigned int* prog,                           // [4]
                int t0, int steps, int tlen)
{
    __shared__ __align__(16) char sH0[2][16384];  // staged h0 (both roles)
    __shared__ __align__(16) char sH1[2][16384];  // staged h1 (role 1 only)

    const int tid  = threadIdx.x;
    const int bid  = blockIdx.x;
    const int role = bid >> 7;
    const int grp  = bid & 3;             // batch group (16 batches)
    const int w    = (bid >> 2) & 31;     // unit slice (16 units)
    const int wv   = tid >> 6;            // wave 0..3
    const int lane = tid & 63;
    const int m16  = lane & 15;           // batch col / A-tile row
    const int q    = lane >> 4;           // k-subgroup / unit-in-wave
    const int ug   = w * 16 + wv * 4 + q; // this lane's unit
    const int bg   = grp * 16 + m16;      // this lane's batch
    const int swz  = (m16 & 7) << 4;

    // --- W fragments (AGPR-resident). A-row r=m16 <-> (gate r&3, du r>>2)
    short8 wahi[16], walo[16];            // recurrent W (Whh0 or Whh1)
    short8 wbhi[16], wblo[16];            // input W (Wih1, role 1 only)
    {
        const size_t rowbase =
            (size_t)((m16 & 3) * H_SZ + w * 16 + wv * 4 + (m16 >> 2)) * H_SZ + q * 8;
        if (role == 0) {
            #pragma unroll
            for (int kk = 0; kk < 16; ++kk) {
                wahi[kk] = *(const short8*)(w0hi + rowbase + kk * 32);
                walo[kk] = *(const short8*)(w0lo + rowbase + kk * 32);
            }
        } else {
            #pragma unroll
            for (int kk = 0; kk < 16; ++kk) {
                wahi[kk] = *(const short8*)(w1ahi + rowbase + kk * 32);
                walo[kk] = *(const short8*)(w1alo + rowbase + kk * 32);
                wbhi[kk] = *(const short8*)(w1bhi + rowbase + kk * 32);
                wblo[kk] = *(const short8*)(w1blo + rowbase + kk * 32);
            }
        }
    }

    float bsum[4] = {0.f, 0.f, 0.f, 0.f};
    if (role == 1) {
        #pragma unroll
        for (int p = 0; p < 4; ++p)
            bsum[p] = bih1[p * H_SZ + ug] + bhh1[p * H_SZ + ug];
    }

    float c_val = (t0 > 0)
        ? c_state[(size_t)role * B_SZ * H_SZ + (size_t)bg * H_SZ + ug] : 0.f;
    float h_prev = 0.f;
    const float* gxp = gx + (size_t)bg * G4H + ug;
    float gxc[4] = {0.f, 0.f, 0.f, 0.f};
    if (role == 0) {
        #pragma unroll
        for (int p = 0; p < 4; ++p) gxc[p] = gxp[p * H_SZ];
    }
    long long polls = 0;

    for (int tt = 0; tt < steps; ++tt) {
        const int t  = t0 + tt;
        const int pb = tt & 1;
        char* dH0 = sH0[pb];
        char* dH1 = sH1[pb];

        // ---- obtain inputs (exact-tag validated; data load IS the sync)
        unsigned v0a[16], v0b[16], v1a[16], v1b[16];
        bool have0 = false;
        if (role == 0) {
            if (t > 0) {
                have0 = true;
                const unsigned e0 = (unsigned)t;          // h0(t-1) tag
                const unsigned int* s0 =
                    hex0 + ((size_t)((t - 1) & 7) * 4 + grp) * 8192 + tid;
                #pragma unroll
                for (int m = 0; m < 16; ++m) {
                    v0a[m] = __hip_atomic_load(s0 + m * 512, __ATOMIC_RELAXED,
                                               __HIP_MEMORY_SCOPE_AGENT);
                    v0b[m] = __hip_atomic_load(s0 + m * 512 + 256, __ATOMIC_RELAXED,
                                               __HIP_MEMORY_SCOPE_AGENT);
                }
                for (;;) {
                    bool ok = true;
                    #pragma unroll
                    for (int m = 0; m < 16; ++m) {
                        if ((v0a[m] & 0xFFFFu) != e0) {
                            v0a[m] = __hip_atomic_load(s0 + m * 512, __ATOMIC_RELAXED,
                                                       __HIP_MEMORY_SCOPE_AGENT);
                            ok = false;
                        }
                        if ((v0b[m] & 0xFFFFu) != e0) {
                            v0b[m] = __hip_atomic_load(s0 + m * 512 + 256, __ATOMIC_RELAXED,
                                                       __HIP_MEMORY_SCOPE_AGENT);
                            ok = false;
                        }
                    }
                    if (ok) break;
                    if (++polls > POLL_BUDGET) break;   // hang safety valve
                }
            }
        } else {
            have0 = true;
            const unsigned e0 = (unsigned)(t + 1);        // h0(t) tag
            const unsigned e1 = (unsigned)t;              // h1(t-1) tag
            const unsigned int* s0 =
                hex0 + ((size_t)(t & 7) * 4 + grp) * 8192 + tid;
            const unsigned int* s1 =
                hex1 + ((size_t)((t - 1) & 7) * 4 + grp) * 8192 + tid;
            #pragma unroll
            for (int m = 0; m < 16; ++m) {
                v0a[m] = __hip_atomic_load(s0 + m * 512, __ATOMIC_RELAXED,
                                           __HIP_MEMORY_SCOPE_AGENT);
                v0b[m] = __hip_atomic_load(s0 + m * 512 + 256, __ATOMIC_RELAXED,
                                           __HIP_MEMORY_SCOPE_AGENT);
            }
            if (t > 0) {
                #pragma unroll
                for (int m = 0; m < 16; ++m) {
                    v1a[m] = __hip_atomic_load(s1 + m * 512, __ATOMIC_RELAXED,
                                               __HIP_MEMORY_SCOPE_AGENT);
                    v1b[m] = __hip_atomic_load(s1 + m * 512 + 256, __ATOMIC_RELAXED,
                                               __HIP_MEMORY_SCOPE_AGENT);
                }
            }
            for (;;) {
                bool ok = true;
                #pragma unroll
                for (int m = 0; m < 16; ++m) {
                    if ((v0a[m] & 0xFFFFu) != e0) {
                        v0a[m] = __hip_atomic_load(s0 + m * 512, __ATOMIC_RELAXED,
                                                   __HIP_MEMORY_SCOPE_AGENT);
                        ok = false;
                    }
                    if ((v0b[m] & 0xFFFFu) != e0) {
                        v0b[m] = __hip_atomic_load(s0 + m * 512 + 256, __ATOMIC_RELAXED,
                                                   __HIP_MEMORY_SCOPE_AGENT);
                        ok = false;
                    }
                }
                if (t > 0) {
                    #pragma unroll
                    for (int m = 0; m < 16; ++m) {
                        if ((v1a[m] & 0xFFFFu) != e1) {
                            v1a[m] = __hip_atomic_load(s1 + m * 512, __ATOMIC_RELAXED,
                                                       __HIP_MEMORY_SCOPE_AGENT);
                            ok = false;
                        }
                        if ((v1b[m] & 0xFFFFu) != e1) {
                            v1b[m] = __hip_atomic_load(s1 + m * 512 + 256, __ATOMIC_RELAXED,
                                                       __HIP_MEMORY_SCOPE_AGENT);
                            ok = false;
                        }
                    }
                }
                if (ok) break;
                if (++polls > POLL_BUDGET) break;   // hang safety valve
            }
            // progress beacon: consumed h0(t) (off the publish latency path)
            if (w == 0 && tid == 0)
                __hip_atomic_store(&prog[grp], (unsigned)(t + 1),
                                   __ATOMIC_RELAXED, __HIP_MEMORY_SCOPE_AGENT);
        }
        asm volatile("" ::: "memory");   // pin off-path ops below the poll

        // ---- off-critical-path: h_out(t-1) (role 1), gx(t+1) / prog (role 0)
        if (role == 1 && tt > 0)
            h_out[((size_t)bg * T_SZ + (t - 1)) * H_SZ + ug] = h_prev;
        float gxn[4] = {0.f, 0.f, 0.f, 0.f};
        unsigned prview = 0xFFFFFFFu;
        if (role == 0) {
            if (tt + 1 < steps) {
                const float* gn = gxp + (size_t)(tt + 1) * (B_SZ * G4H);
                #pragma unroll
                for (int p = 0; p < 4; ++p) gxn[p] = gn[p * H_SZ];
            }
            prview = __hip_atomic_load(&prog[grp], __ATOMIC_RELAXED,
                                       __HIP_MEMORY_SCOPE_AGENT);
        }

        // ---- stage into swizzled LDS
        if (have0) {
            #pragma unroll
            for (int m = 0; m < 16; ++m) {
                const int oa = ((m << 10) + 2 * tid) ^ ((m & 7) << 4);
                const int ob = ((m << 10) + 2 * (tid + 256)) ^ ((m & 7) << 4);
                *(unsigned short*)(dH0 + oa) = (unsigned short)(v0a[m] >> 16);
                *(unsigned short*)(dH0 + ob) = (unsigned short)(v0b[m] >> 16);
            }
        } else {   // role 0, t == 0
            const float4 z = {0.f, 0.f, 0.f, 0.f};
            #pragma unroll
            for (int s = 0; s < 4; ++s)
                *(float4*)(dH0 + tid * 16 + s * 4096) = z;
        }
        if (role == 1) {
            if (t == 0) {
                const float4 z = {0.f, 0.f, 0.f, 0.f};
                #pragma unroll
                for (int s = 0; s < 4; ++s)
                    *(float4*)(dH1 + tid * 16 + s * 4096) = z;
            } else {
                #pragma unroll
                for (int m = 0; m < 16; ++m) {
                    const int oa = ((m << 10) + 2 * tid) ^ ((m & 7) << 4);
                    const int ob = ((m << 10) + 2 * (tid + 256)) ^ ((m & 7) << 4);
                    *(unsigned short*)(dH1 + oa) = (unsigned short)(v1a[m] >> 16);
                    *(unsigned short*)(dH1 + ob) = (unsigned short)(v1b[m] >> 16);
                }
            }
        }
        __syncthreads();   // the ONLY barrier per step

        // ---- MFMA: recurrent product (+ input product for role 1)
        f32x4 a0 = {0.f, 0.f, 0.f, 0.f};
        f32x4 a2 = {0.f, 0.f, 0.f, 0.f};
        const char* hrec = (role == 0 ? dH0 : dH1) + (m16 << 10);
        const char* hinp = dH0 + (m16 << 10);
        #pragma unroll
        for (int kk = 0; kk < 16; ++kk) {
            const int off = (kk * 64 + q * 16) ^ swz;
            const short8 hr = *(const short8*)(hrec + off);
            a0 = __builtin_amdgcn_mfma_f32_16x16x32_bf16(wahi[kk], hr, a0, 0, 0, 0);
            a2 = __builtin_amdgcn_mfma_f32_16x16x32_bf16(walo[kk], hr, a2, 0, 0, 0);
            if (role == 1) {
                const short8 h0v = *(const short8*)(hinp + off);
                a0 = __builtin_amdgcn_mfma_f32_16x16x32_bf16(wbhi[kk], h0v, a0, 0, 0, 0);
                a2 = __builtin_amdgcn_mfma_f32_16x16x32_bf16(wblo[kk], h0v, a2, 0, 0, 0);
            }
        }

        // ---- in-lane update + publish (acc reg p = gate p for (bg, ug))
        {
            const float base0 = (role == 0) ? gxc[0] : bsum[0];
            const float base1 = (role == 0) ? gxc[1] : bsum[1];
            const float base2 = (role == 0) ? gxc[2] : bsum[2];
            const float base3 = (role == 0) ? gxc[3] : bsum[3];
            const float si = sigmoid_f(a0[0] + a2[0] + base0);
            const float sf = sigmoid_f(a0[1] + a2[1] + base1);
            const float tc = tanh_f(a0[2] + a2[2] + base2);
            const float so = sigmoid_f(a0[3] + a2[3] + base3);
            c_val = sf * c_val + si * tc;
            const float h = so * tanh_f(c_val);
            const unsigned val = (((unsigned)f2bf_rne(h)) << 16) | (unsigned)(t + 1);
            if (role == 0) {
                // h0-ring overwrite guard: layer 1 must have consumed h0(t-8)
                while ((int)prview < t - 6) {
                    if (++polls > POLL_BUDGET) break;
                    prview = __hip_atomic_load(&prog[grp], __ATOMIC_RELAXED,
                                               __HIP_MEMORY_SCOPE_AGENT);
                }
                __hip_atomic_store(hex0 + ((size_t)(t & 7) * 4 + grp) * 8192
                                        + m16 * 512 + ug,
                                   val, __ATOMIC_RELAXED, __HIP_MEMORY_SCOPE_AGENT);
            } else {
                __hip_atomic_store(hex1 + ((size_t)(t & 7) * 4 + grp) * 8192
                                        + m16 * 512 + ug,
                                   val, __ATOMIC_RELAXED, __HIP_MEMORY_SCOPE_AGENT);
                h_prev = h;
            }
        }
        #pragma unroll
        for (int p = 0; p < 4; ++p) gxc[p] = gxn[p];
    }
    // deferred last h_out store + cross-chunk c carry
    if (role == 1)
        h_out[((size_t)bg * T_SZ + (t0 + steps - 1)) * H_SZ + ug] = h_prev;
    if (t0 + steps < T_SZ)
        c_state[(size_t)role * B_SZ * H_SZ + (size_t)bg * H_SZ + ug] = c_val;
}

// Beacon: surfaces ws_size (MiB) through the absmax error if ws is too small.
__global__ void debug_ws_beacon(float* out, float v)
{
    if (threadIdx.x == 0 && blockIdx.x == 0) out[0] = v;
}

// ---------------------------------------------------------------------------
extern "C" void kernel_launch(void* const* d_in, const int* in_sizes, int n_in,
                              void* d_out, int out_size, void* d_ws, size_t ws_size,
                              hipStream_t stream)
{
    const float* x    = (const float*)d_in[0];
    const float* Wih0 = (const float*)d_in[1];
    const float* Whh0 = (const float*)d_in[2];
    const float* bih0 = (const float*)d_in[3];
    const float* bhh0 = (const float*)d_in[4];
    const float* Wih1 = (const float*)d_in[5];
    const float* Whh1 = (const float*)d_in[6];
    const float* bih1 = (const float*)d_in[7];
    const float* bhh1 = (const float*)d_in[8];
    float* out = (float*)d_out;

    const size_t ringB = (size_t)8 * 4 * 16 * H_SZ * 4;   // 1 MiB per ring
    const size_t cstB  = (size_t)2 * B_SZ * H_SZ * 4;     // 256 KiB
    const size_t prgB  = 256;
    const size_t wB    = (size_t)G4H * H_SZ * 2;          // 2 MiB per matrix
    const size_t fixed = 2 * ringB + cstB + prgB + 6 * wB;

    static const int opts[] = {1536, 768, 512, 384, 256, 128};
    int T_CHUNK = 0;
    for (int i = 0; i < 6; ++i) {
        const size_t need = (size_t)B_SZ * G4H * opts[i] * 4 + fixed;
        if (need <= ws_size) { T_CHUNK = opts[i]; break; }
    }
    if (T_CHUNK == 0) {
        debug_ws_beacon<<<1, 1, 0, stream>>>(out, (float)(ws_size >> 20));
        return;
    }

    char* ws = (char*)d_ws;
    const size_t gxB = (size_t)B_SZ * G4H * T_CHUNK * 4;
    float*          gx      = (float*)ws;
    unsigned int*   hex0    = (unsigned int*)(ws + gxB);
    unsigned int*   hex1    = (unsigned int*)(ws + gxB + ringB);
    float*          c_state = (float*)(ws + gxB + 2 * ringB);
    unsigned int*   prog    = (unsigned int*)(ws + gxB + 2 * ringB + cstB);
    unsigned short* w0hi    = (unsigned short*)(ws + gxB + 2 * ringB + cstB + prgB);
    unsigned short* w0lo    = w0hi  + G4H * H_SZ;
    unsigned short* w1ahi   = w0lo  + G4H * H_SZ;
    unsigned short* w1alo   = w1ahi + G4H * H_SZ;
    unsigned short* w1bhi   = w1alo + G4H * H_SZ;
    unsigned short* w1blo   = w1bhi + G4H * H_SZ;

    const int nW = G4H * H_SZ;
    wsplit<<<(nW + 255) / 256, 256, 0, stream>>>(Whh0, w0hi, w0lo, nW);
    wsplit<<<(nW + 255) / 256, 256, 0, stream>>>(Whh1, w1ahi, w1alo, nW);
    wsplit<<<(nW + 255) / 256, 256, 0, stream>>>(Wih1, w1bhi, w1blo, nW);

    // fresh tags + progress each call (replay safety: tag 0 never valid)
    hipMemsetAsync(hex0, 0, 2 * ringB, stream);
    hipMemsetAsync(prog, 0, prgB, stream);

    const dim3 ggrid(T_CHUNK / 128, G4H / 128, B_SZ);
    for (int t0 = 0; t0 < T_SZ; t0 += T_CHUNK) {
        gemm_gx<0><<<ggrid, 256, 0, stream>>>(x, Wih0, bih0, bhh0, gx, C_SZ,
                                              C_SZ * T_SZ, t0, T_CHUNK);
        lstm_fused<<<256, 256, 0, stream>>>(gx, w0hi, w0lo, w1ahi, w1alo,
                                            w1bhi, w1blo, bih1, bhh1, out,
                                            hex0, hex1, c_state, prog,
                                            t0, T_CHUNK, T_CHUNK);
    }
}

// Round 14
// 12255.573 us; speedup vs baseline: 1.9056x; 1.2387x over previous
//
#include <hip/hip_runtime.h>
#include <cstdint>
#include <cstddef>

#define B_SZ 64
#define T_SZ 1536
#define C_SZ 256
#define H_SZ 512
#define G4H  2048
#define POLL_BUDGET 5000000

typedef __attribute__((ext_vector_type(8))) short short8;
typedef __attribute__((ext_vector_type(4))) float f32x4;

__device__ __forceinline__ unsigned short f2bf_rne(float f) {
    unsigned u = __float_as_uint(f);
    unsigned r = (u + 0x7FFF + ((u >> 16) & 1)) >> 16;
    return (unsigned short)r;
}
__device__ __forceinline__ float sigmoid_f(float x) {
    return 1.f / (1.f + __expf(-x));
}
__device__ __forceinline__ float tanh_f(float x) {
    return 1.f - 2.f / (__expf(2.f * x) + 1.f);
}

// ---------------------------------------------------------------------------
// Input GEMM for layer 0 only (verified R2-R13). Output [tlen][B][4H].
// ---------------------------------------------------------------------------
template<int AMODE>
__global__ __launch_bounds__(256)
void gemm_gx(const float* __restrict__ A, const float* __restrict__ W,
             const float* __restrict__ bias1, const float* __restrict__ bias2,
             float* __restrict__ gx, int K, int astride_b, int t0g, int tlen)
{
    __shared__ float a_s[8][132];
    __shared__ float b_s[8][132];
    const int tb = blockIdx.x, nb = blockIdx.y, b = blockIdx.z;
    const int tloc = tb * 128;
    const int tglb = t0g + tloc;
    const int r0 = nb * 128;
    const float* Ab = A + (size_t)b * astride_b;
    const int tid = threadIdx.x;
    const int tx = tid & 15, ty = tid >> 4;
    float acc[8][8] = {};

    for (int k0 = 0; k0 < K; k0 += 8) {
        if (AMODE == 0) {
            const int row = tid >> 5;
            const int col = (tid & 31) << 2;
            const float4 v = *(const float4*)(Ab + (size_t)(k0 + row) * T_SZ + tglb + col);
            *(float4*)&a_s[row][col] = v;
        } else {
            const int row  = tid >> 1;
            const int half = (tid & 1) << 2;
            const float4 v = *(const float4*)(Ab + (size_t)(tglb + row) * H_SZ + k0 + half);
            a_s[half + 0][row] = v.x; a_s[half + 1][row] = v.y;
            a_s[half + 2][row] = v.z; a_s[half + 3][row] = v.w;
        }
        {
            const int row  = tid >> 1;
            const int half = (tid & 1) << 2;
            const float4 v = *(const float4*)(W + (size_t)(r0 + row) * K + k0 + half);
            b_s[half + 0][row] = v.x; b_s[half + 1][row] = v.y;
            b_s[half + 2][row] = v.z; b_s[half + 3][row] = v.w;
        }
        __syncthreads();
        #pragma unroll
        for (int kk = 0; kk < 8; ++kk) {
            float4 a0 = *(const float4*)&a_s[kk][tx * 8];
            float4 a1 = *(const float4*)&a_s[kk][tx * 8 + 4];
            float4 w0 = *(const float4*)&b_s[kk][ty * 8];
            float4 w1 = *(const float4*)&b_s[kk][ty * 8 + 4];
            float av[8] = {a0.x, a0.y, a0.z, a0.w, a1.x, a1.y, a1.z, a1.w};
            float wv[8] = {w0.x, w0.y, w0.z, w0.w, w1.x, w1.y, w1.z, w1.w};
            #pragma unroll
            for (int i = 0; i < 8; ++i)
                #pragma unroll
                for (int j = 0; j < 8; ++j)
                    acc[i][j] += wv[i] * av[j];
        }
        __syncthreads();
    }
    float bs[8];
    #pragma unroll
    for (int i = 0; i < 8; ++i)
        bs[i] = bias1[r0 + ty * 8 + i] + bias2[r0 + ty * 8 + i];
    #pragma unroll
    for (int j = 0; j < 8; ++j) {
        float* dst = gx + ((size_t)(tloc + tx * 8 + j) * B_SZ + b) * G4H + r0 + ty * 8;
        float4 o0 = {acc[0][j] + bs[0], acc[1][j] + bs[1], acc[2][j] + bs[2], acc[3][j] + bs[3]};
        float4 o1 = {acc[4][j] + bs[4], acc[5][j] + bs[5], acc[6][j] + bs[6], acc[7][j] + bs[7]};
        *(float4*)dst = o0; *(float4*)(dst + 4) = o1;
    }
}

// ---------------------------------------------------------------------------
__global__ void wsplit(const float* __restrict__ w,
                       unsigned short* __restrict__ hi,
                       unsigned short* __restrict__ lo, int n)
{
    const int i = blockIdx.x * 256 + threadIdx.x;
    if (i < n) {
        const float v = w[i];
        const unsigned short h = f2bf_rne(v);
        hi[i] = h;
        lo[i] = f2bf_rne(v - __uint_as_float(((unsigned)h) << 16));
    }
}

// ---------------------------------------------------------------------------
// FUSED two-layer LSTM scan v12 = R13 verified structure + PER-WAVE FLAG
// GATING of the consumer spin. R13's spin re-loaded 32 data values per
// thread per retry (FETCH 808MB vs 403MB gx -> ~0.5MB/step of HBM/L3 spin
// traffic = the congestion floor). Now: producer wave stores its 64 values,
// drains vmcnt(0), lane0 stores ONE flag (= t+1). Consumer threads spin on
// the 2 flags covering their 2 units (8 cache lines/WG/retry vs 32KB), then
// load data ONCE; exact-tag validation stays as the relaxed-ordering
// backstop (flag may outrun data; tags catch it; micro-retry rare).
// Everything else identical to R13 (roles, rings, prog guard, W in AGPRs).
// ---------------------------------------------------------------------------
__global__ __launch_bounds__(256, 1)
void lstm_fused(const float* __restrict__ gx,                 // [tlen][B][4H]
                const unsigned short* __restrict__ w0hi,      // Whh0 [4H][H]
                const unsigned short* __restrict__ w0lo,
                const unsigned short* __restrict__ w1ahi,     // Whh1
                const unsigned short* __restrict__ w1alo,
                const unsigned short* __restrict__ w1bhi,     // Wih1
                const unsigned short* __restrict__ w1blo,
                const float* __restrict__ bih1,
                const float* __restrict__ bhh1,
                float* __restrict__ h_out,                    // [B][T][H]
                unsigned int* hex0,                           // [8][4][16][512]
                unsigned int* hex1,                           // [8][4][16][512]
                float* __restrict__ c_state,                  // [2][B][H]
                unsigned int* prog,                           // [4]
                unsigned int* flag0,                          // [4][128]
                unsigned int* flag1,                          // [4][128]
                int t0, int steps, int tlen)
{
    __shared__ __align__(16) char sH0[2][16384];  // staged h0 (both roles)
    __shared__ __align__(16) char sH1[2][16384];  // staged h1 (role 1 only)

    const int tid  = threadIdx.x;
    const int bid  = blockIdx.x;
    const int role = bid >> 7;
    const int grp  = bid & 3;             // batch group (16 batches)
    const int w    = (bid >> 2) & 31;     // unit slice (16 units)
    const int wv   = tid >> 6;            // wave 0..3
    const int lane = tid & 63;
    const int m16  = lane & 15;           // batch col / A-tile row
    const int q    = lane >> 4;           // k-subgroup / unit-in-wave
    const int ug   = w * 16 + wv * 4 + q; // this lane's unit
    const int bg   = grp * 16 + m16;      // this lane's batch
    const int swz  = (m16 & 7) << 4;

    // flag addresses: producer wave (w,wv) -> index w*4+wv; consumer thread
    // tid needs units {tid, tid+256} -> indices (tid>>4)*4+((tid&15)>>2), +64
    const int fidx = ((tid >> 4) << 2) + ((tid & 15) >> 2);
    unsigned int* f0g = flag0 + grp * 128;
    unsigned int* f1g = flag1 + grp * 128;
    const int pidx = w * 4 + wv;          // this wave's producer flag

    // --- W fragments (AGPR-resident). A-row r=m16 <-> (gate r&3, du r>>2)
    short8 wahi[16], walo[16];            // recurrent W (Whh0 or Whh1)
    short8 wbhi[16], wblo[16];            // input W (Wih1, role 1 only)
    {
        const size_t rowbase =
            (size_t)((m16 & 3) * H_SZ + w * 16 + wv * 4 + (m16 >> 2)) * H_SZ + q * 8;
        if (role == 0) {
            #pragma unroll
            for (int kk = 0; kk < 16; ++kk) {
                wahi[kk] = *(const short8*)(w0hi + rowbase + kk * 32);
                walo[kk] = *(const short8*)(w0lo + rowbase + kk * 32);
            }
        } else {
            #pragma unroll
            for (int kk = 0; kk < 16; ++kk) {
                wahi[kk] = *(const short8*)(w1ahi + rowbase + kk * 32);
                walo[kk] = *(const short8*)(w1alo + rowbase + kk * 32);
                wbhi[kk] = *(const short8*)(w1bhi + rowbase + kk * 32);
                wblo[kk] = *(const short8*)(w1blo + rowbase + kk * 32);
            }
        }
    }

    float bsum[4] = {0.f, 0.f, 0.f, 0.f};
    if (role == 1) {
        #pragma unroll
        for (int p = 0; p < 4; ++p)
            bsum[p] = bih1[p * H_SZ + ug] + bhh1[p * H_SZ + ug];
    }

    float c_val = (t0 > 0)
        ? c_state[(size_t)role * B_SZ * H_SZ + (size_t)bg * H_SZ + ug] : 0.f;
    float h_prev = 0.f;
    const float* gxp = gx + (size_t)bg * G4H + ug;
    float gxc[4] = {0.f, 0.f, 0.f, 0.f};
    if (role == 0) {
        #pragma unroll
        for (int p = 0; p < 4; ++p) gxc[p] = gxp[p * H_SZ];
    }
    long long polls = 0;

    for (int tt = 0; tt < steps; ++tt) {
        const int t  = t0 + tt;
        const int pb = tt & 1;
        char* dH0 = sH0[pb];
        char* dH1 = sH1[pb];

        // ---- flag gates (cheap spin: 2-3 lines/wave/retry), then data ONCE
        unsigned v0a[16], v0b[16], v1a[16], v1b[16];
        bool have0 = false;
        if (role == 0) {
            if (t > 0) {
                have0 = true;
                const unsigned tg0 = (unsigned)t;        // h0(t-1)
                while (__hip_atomic_load(f0g + fidx, __ATOMIC_RELAXED,
                                         __HIP_MEMORY_SCOPE_AGENT) < tg0)
                    if (++polls > POLL_BUDGET) break;
                while (__hip_atomic_load(f0g + fidx + 64, __ATOMIC_RELAXED,
                                         __HIP_MEMORY_SCOPE_AGENT) < tg0)
                    if (++polls > POLL_BUDGET) break;
                asm volatile("" ::: "memory");
                const unsigned int* s0 =
                    hex0 + ((size_t)((t - 1) & 7) * 4 + grp) * 8192 + tid;
                #pragma unroll
                for (int m = 0; m < 16; ++m) {
                    v0a[m] = __hip_atomic_load(s0 + m * 512, __ATOMIC_RELAXED,
                                               __HIP_MEMORY_SCOPE_AGENT);
                    v0b[m] = __hip_atomic_load(s0 + m * 512 + 256, __ATOMIC_RELAXED,
                                               __HIP_MEMORY_SCOPE_AGENT);
                }
                for (;;) {   // tag backstop (rarely loops)
                    bool ok = true;
                    #pragma unroll
                    for (int m = 0; m < 16; ++m) {
                        if ((v0a[m] & 0xFFFFu) != tg0) {
                            v0a[m] = __hip_atomic_load(s0 + m * 512, __ATOMIC_RELAXED,
                                                       __HIP_MEMORY_SCOPE_AGENT);
                            ok = false;
                        }
                        if ((v0b[m] & 0xFFFFu) != tg0) {
                            v0b[m] = __hip_atomic_load(s0 + m * 512 + 256, __ATOMIC_RELAXED,
                                                       __HIP_MEMORY_SCOPE_AGENT);
                            ok = false;
                        }
                    }
                    if (ok) break;
                    if (++polls > POLL_BUDGET) break;
                }
            }
        } else {
            have0 = true;
            const unsigned tg0 = (unsigned)(t + 1);      // h0(t)
            const unsigned tg1 = (unsigned)t;            // h1(t-1)
            while (__hip_atomic_load(f0g + fidx, __ATOMIC_RELAXED,
                                     __HIP_MEMORY_SCOPE_AGENT) < tg0)
                if (++polls > POLL_BUDGET) break;
            while (__hip_atomic_load(f0g + fidx + 64, __ATOMIC_RELAXED,
                                     __HIP_MEMORY_SCOPE_AGENT) < tg0)
                if (++polls > POLL_BUDGET) break;
            if (t > 0) {
                while (__hip_atomic_load(f1g + fidx, __ATOMIC_RELAXED,
                                         __HIP_MEMORY_SCOPE_AGENT) < tg1)
                    if (++polls > POLL_BUDGET) break;
                while (__hip_atomic_load(f1g + fidx + 64, __ATOMIC_RELAXED,
                                         __HIP_MEMORY_SCOPE_AGENT) < tg1)
                    if (++polls > POLL_BUDGET) break;
            }
            asm volatile("" ::: "memory");
            const unsigned int* s0 =
                hex0 + ((size_t)(t & 7) * 4 + grp) * 8192 + tid;
            const unsigned int* s1 =
                hex1 + ((size_t)((t - 1) & 7) * 4 + grp) * 8192 + tid;
            #pragma unroll
            for (int m = 0; m < 16; ++m) {
                v0a[m] = __hip_atomic_load(s0 + m * 512, __ATOMIC_RELAXED,
                                           __HIP_MEMORY_SCOPE_AGENT);
                v0b[m] = __hip_atomic_load(s0 + m * 512 + 256, __ATOMIC_RELAXED,
                                           __HIP_MEMORY_SCOPE_AGENT);
            }
            if (t > 0) {
                #pragma unroll
                for (int m = 0; m < 16; ++m) {
                    v1a[m] = __hip_atomic_load(s1 + m * 512, __ATOMIC_RELAXED,
                                               __HIP_MEMORY_SCOPE_AGENT);
                    v1b[m] = __hip_atomic_load(s1 + m * 512 + 256, __ATOMIC_RELAXED,
                                               __HIP_MEMORY_SCOPE_AGENT);
                }
            }
            for (;;) {   // tag backstop
                bool ok = true;
                #pragma unroll
                for (int m = 0; m < 16; ++m) {
                    if ((v0a[m] & 0xFFFFu) != tg0) {
                        v0a[m] = __hip_atomic_load(s0 + m * 512, __ATOMIC_RELAXED,
                                                   __HIP_MEMORY_SCOPE_AGENT);
                        ok = false;
                    }
                    if ((v0b[m] & 0xFFFFu) != tg0) {
                        v0b[m] = __hip_atomic_load(s0 + m * 512 + 256, __ATOMIC_RELAXED,
                                                   __HIP_MEMORY_SCOPE_AGENT);
                        ok = false;
                    }
                }
                if (t > 0) {
                    #pragma unroll
                    for (int m = 0; m < 16; ++m) {
                        if ((v1a[m] & 0xFFFFu) != tg1) {
                            v1a[m] = __hip_atomic_load(s1 + m * 512, __ATOMIC_RELAXED,
                                                       __HIP_MEMORY_SCOPE_AGENT);
                            ok = false;
                        }
                        if ((v1b[m] & 0xFFFFu) != tg1) {
                            v1b[m] = __hip_atomic_load(s1 + m * 512 + 256, __ATOMIC_RELAXED,
                                                       __HIP_MEMORY_SCOPE_AGENT);
                            ok = false;
                        }
                    }
                }
                if (ok) break;
                if (++polls > POLL_BUDGET) break;
            }
            // progress beacon: consumed h0(t) (off the publish latency path)
            if (w == 0 && tid == 0)
                __hip_atomic_store(&prog[grp], (unsigned)(t + 1),
                                   __ATOMIC_RELAXED, __HIP_MEMORY_SCOPE_AGENT);
        }
        asm volatile("" ::: "memory");   // pin off-path ops below the poll

        // ---- off-critical-path: h_out(t-1) (role 1), gx(t+1) / prog (role 0)
        if (role == 1 && tt > 0)
            h_out[((size_t)bg * T_SZ + (t - 1)) * H_SZ + ug] = h_prev;
        float gxn[4] = {0.f, 0.f, 0.f, 0.f};
        unsigned prview = 0xFFFFFFFu;
        if (role == 0) {
            if (tt + 1 < steps) {
                const float* gn = gxp + (size_t)(tt + 1) * (B_SZ * G4H);
                #pragma unroll
                for (int p = 0; p < 4; ++p) gxn[p] = gn[p * H_SZ];
            }
            prview = __hip_atomic_load(&prog[grp], __ATOMIC_RELAXED,
                                       __HIP_MEMORY_SCOPE_AGENT);
        }

        // ---- stage into swizzled LDS
        if (have0) {
            #pragma unroll
            for (int m = 0; m < 16; ++m) {
                const int oa = ((m << 10) + 2 * tid) ^ ((m & 7) << 4);
                const int ob = ((m << 10) + 2 * (tid + 256)) ^ ((m & 7) << 4);
                *(unsigned short*)(dH0 + oa) = (unsigned short)(v0a[m] >> 16);
                *(unsigned short*)(dH0 + ob) = (unsigned short)(v0b[m] >> 16);
            }
        } else {   // role 0, t == 0
            const float4 z = {0.f, 0.f, 0.f, 0.f};
            #pragma unroll
            for (int s = 0; s < 4; ++s)
                *(float4*)(dH0 + tid * 16 + s * 4096) = z;
        }
        if (role == 1) {
            if (t == 0) {
                const float4 z = {0.f, 0.f, 0.f, 0.f};
                #pragma unroll
                for (int s = 0; s < 4; ++s)
                    *(float4*)(dH1 + tid * 16 + s * 4096) = z;
            } else {
                #pragma unroll
                for (int m = 0; m < 16; ++m) {
                    const int oa = ((m << 10) + 2 * tid) ^ ((m & 7) << 4);
                    const int ob = ((m << 10) + 2 * (tid + 256)) ^ ((m & 7) << 4);
                    *(unsigned short*)(dH1 + oa) = (unsigned short)(v1a[m] >> 16);
                    *(unsigned short*)(dH1 + ob) = (unsigned short)(v1b[m] >> 16);
                }
            }
        }
        __syncthreads();   // the ONLY barrier per step

        // ---- MFMA: recurrent product (+ input product for role 1)
        f32x4 a0 = {0.f, 0.f, 0.f, 0.f};
        f32x4 a2 = {0.f, 0.f, 0.f, 0.f};
        const char* hrec = (role == 0 ? dH0 : dH1) + (m16 << 10);
        const char* hinp = dH0 + (m16 << 10);
        #pragma unroll
        for (int kk = 0; kk < 16; ++kk) {
            const int off = (kk * 64 + q * 16) ^ swz;
            const short8 hr = *(const short8*)(hrec + off);
            a0 = __builtin_amdgcn_mfma_f32_16x16x32_bf16(wahi[kk], hr, a0, 0, 0, 0);
            a2 = __builtin_amdgcn_mfma_f32_16x16x32_bf16(walo[kk], hr, a2, 0, 0, 0);
            if (role == 1) {
                const short8 h0v = *(const short8*)(hinp + off);
                a0 = __builtin_amdgcn_mfma_f32_16x16x32_bf16(wbhi[kk], h0v, a0, 0, 0, 0);
                a2 = __builtin_amdgcn_mfma_f32_16x16x32_bf16(wblo[kk], h0v, a2, 0, 0, 0);
            }
        }

        // ---- in-lane update + publish + per-wave flag
        {
            const float base0 = (role == 0) ? gxc[0] : bsum[0];
            const float base1 = (role == 0) ? gxc[1] : bsum[1];
            const float base2 = (role == 0) ? gxc[2] : bsum[2];
            const float base3 = (role == 0) ? gxc[3] : bsum[3];
            const float si = sigmoid_f(a0[0] + a2[0] + base0);
            const float sf = sigmoid_f(a0[1] + a2[1] + base1);
            const float tc = tanh_f(a0[2] + a2[2] + base2);
            const float so = sigmoid_f(a0[3] + a2[3] + base3);
            c_val = sf * c_val + si * tc;
            const float h = so * tanh_f(c_val);
            const unsigned val = (((unsigned)f2bf_rne(h)) << 16) | (unsigned)(t + 1);
            if (role == 0) {
                // h0-ring overwrite guard: layer 1 must have consumed h0(t-8)
                while ((int)prview < t - 6) {
                    if (++polls > POLL_BUDGET) break;
                    prview = __hip_atomic_load(&prog[grp], __ATOMIC_RELAXED,
                                               __HIP_MEMORY_SCOPE_AGENT);
                }
                __hip_atomic_store(hex0 + ((size_t)(t & 7) * 4 + grp) * 8192
                                        + m16 * 512 + ug,
                                   val, __ATOMIC_RELAXED, __HIP_MEMORY_SCOPE_AGENT);
                asm volatile("s_waitcnt vmcnt(0)" ::: "memory");
                if (lane == 0)
                    __hip_atomic_store(f0g + pidx, (unsigned)(t + 1),
                                       __ATOMIC_RELAXED, __HIP_MEMORY_SCOPE_AGENT);
            } else {
                __hip_atomic_store(hex1 + ((size_t)(t & 7) * 4 + grp) * 8192
                                        + m16 * 512 + ug,
                                   val, __ATOMIC_RELAXED, __HIP_MEMORY_SCOPE_AGENT);
                asm volatile("s_waitcnt vmcnt(0)" ::: "memory");
                if (lane == 0)
                    __hip_atomic_store(f1g + pidx, (unsigned)(t + 1),
                                       __ATOMIC_RELAXED, __HIP_MEMORY_SCOPE_AGENT);
                h_prev = h;
            }
        }
        #pragma unroll
        for (int p = 0; p < 4; ++p) gxc[p] = gxn[p];
    }
    // deferred last h_out store + cross-chunk c carry
    if (role == 1)
        h_out[((size_t)bg * T_SZ + (t0 + steps - 1)) * H_SZ + ug] = h_prev;
    if (t0 + steps < T_SZ)
        c_state[(size_t)role * B_SZ * H_SZ + (size_t)bg * H_SZ + ug] = c_val;
}

// Beacon: surfaces ws_size (MiB) through the absmax error if ws is too small.
__global__ void debug_ws_beacon(float* out, float v)
{
    if (threadIdx.x == 0 && blockIdx.x == 0) out[0] = v;
}

// ---------------------------------------------------------------------------
extern "C" void kernel_launch(void* const* d_in, const int* in_sizes, int n_in,
                              void* d_out, int out_size, void* d_ws, size_t ws_size,
                              hipStream_t stream)
{
    const float* x    = (const float*)d_in[0];
    const float* Wih0 = (const float*)d_in[1];
    const float* Whh0 = (const float*)d_in[2];
    const float* bih0 = (const float*)d_in[3];
    const float* bhh0 = (const float*)d_in[4];
    const float* Wih1 = (const float*)d_in[5];
    const float* Whh1 = (const float*)d_in[6];
    const float* bih1 = (const float*)d_in[7];
    const float* bhh1 = (const float*)d_in[8];
    float* out = (float*)d_out;

    const size_t ringB = (size_t)8 * 4 * 16 * H_SZ * 4;   // 1 MiB per ring
    const size_t cstB  = (size_t)2 * B_SZ * H_SZ * 4;     // 256 KiB
    const size_t prgB  = 8192;                            // prog + flags
    const size_t wB    = (size_t)G4H * H_SZ * 2;          // 2 MiB per matrix
    const size_t fixed = 2 * ringB + cstB + prgB + 6 * wB;

    static const int opts[] = {1536, 768, 512, 384, 256, 128};
    int T_CHUNK = 0;
    for (int i = 0; i < 6; ++i) {
        const size_t need = (size_t)B_SZ * G4H * opts[i] * 4 + fixed;
        if (need <= ws_size) { T_CHUNK = opts[i]; break; }
    }
    if (T_CHUNK == 0) {
        debug_ws_beacon<<<1, 1, 0, stream>>>(out, (float)(ws_size >> 20));
        return;
    }

    char* ws = (char*)d_ws;
    const size_t gxB = (size_t)B_SZ * G4H * T_CHUNK * 4;
    float*          gx      = (float*)ws;
    unsigned int*   hex0    = (unsigned int*)(ws + gxB);
    unsigned int*   hex1    = (unsigned int*)(ws + gxB + ringB);
    float*          c_state = (float*)(ws + gxB + 2 * ringB);
    unsigned int*   prog    = (unsigned int*)(ws + gxB + 2 * ringB + cstB);
    unsigned int*   flag0   = prog + 64;                  // [4][128]
    unsigned int*   flag1   = flag0 + 512;                // [4][128]
    unsigned short* w0hi    = (unsigned short*)(ws + gxB + 2 * ringB + cstB + prgB);
    unsigned short* w0lo    = w0hi  + G4H * H_SZ;
    unsigned short* w1ahi   = w0lo  + G4H * H_SZ;
    unsigned short* w1alo   = w1ahi + G4H * H_SZ;
    unsigned short* w1bhi   = w1alo + G4H * H_SZ;
    unsigned short* w1blo   = w1bhi + G4H * H_SZ;

    const int nW = G4H * H_SZ;
    wsplit<<<(nW + 255) / 256, 256, 0, stream>>>(Whh0, w0hi, w0lo, nW);
    wsplit<<<(nW + 255) / 256, 256, 0, stream>>>(Whh1, w1ahi, w1alo, nW);
    wsplit<<<(nW + 255) / 256, 256, 0, stream>>>(Wih1, w1bhi, w1blo, nW);

    // fresh tags + flags each call (replay safety: tag/flag 0 never valid)
    hipMemsetAsync(hex0, 0, 2 * ringB, stream);
    hipMemsetAsync(prog, 0, prgB, stream);

    const dim3 ggrid(T_CHUNK / 128, G4H / 128, B_SZ);
    for (int t0 = 0; t0 < T_SZ; t0 += T_CHUNK) {
        gemm_gx<0><<<ggrid, 256, 0, stream>>>(x, Wih0, bih0, bhh0, gx, C_SZ,
                                              C_SZ * T_SZ, t0, T_CHUNK);
        lstm_fused<<<256, 256, 0, stream>>>(gx, w0hi, w0lo, w1ahi, w1alo,
                                            w1bhi, w1blo, bih1, bhh1, out,
                                            hex0, hex1, c_state, prog,
                                            flag0, flag1, t0, T_CHUNK, T_CHUNK);
    }
}

// Round 15
// 11224.670 us; speedup vs baseline: 2.0806x; 1.0918x over previous
//
#include <hip/hip_runtime.h>
#include <cstdint>
#include <cstddef>

#define B_SZ 64
#define T_SZ 1536
#define C_SZ 256
#define H_SZ 512
#define G4H  2048
#define POLL_BUDGET 5000000

typedef __attribute__((ext_vector_type(8))) short short8;
typedef __attribute__((ext_vector_type(4))) float f32x4;

#define AL(p) __hip_atomic_load((p), __ATOMIC_RELAXED, __HIP_MEMORY_SCOPE_AGENT)
#define AS(p, x) __hip_atomic_store((p), (x), __ATOMIC_RELAXED, __HIP_MEMORY_SCOPE_AGENT)
#define SPIN_GE(p, tgt) \
    while (AL(p) < (tgt)) { if (++polls > POLL_BUDGET) break; }

__device__ __forceinline__ unsigned short f2bf_rne(float f) {
    unsigned u = __float_as_uint(f);
    unsigned r = (u + 0x7FFF + ((u >> 16) & 1)) >> 16;
    return (unsigned short)r;
}
__device__ __forceinline__ float sigmoid_f(float x) {
    return 1.f / (1.f + __expf(-x));
}
__device__ __forceinline__ float tanh_f(float x) {
    return 1.f - 2.f / (__expf(2.f * x) + 1.f);
}

// ---------------------------------------------------------------------------
// Input GEMM for layer 0 only (verified R2-R14). Output [tlen][B][4H].
// ---------------------------------------------------------------------------
template<int AMODE>
__global__ __launch_bounds__(256)
void gemm_gx(const float* __restrict__ A, const float* __restrict__ W,
             const float* __restrict__ bias1, const float* __restrict__ bias2,
             float* __restrict__ gx, int K, int astride_b, int t0g, int tlen)
{
    __shared__ float a_s[8][132];
    __shared__ float b_s[8][132];
    const int tb = blockIdx.x, nb = blockIdx.y, b = blockIdx.z;
    const int tloc = tb * 128;
    const int tglb = t0g + tloc;
    const int r0 = nb * 128;
    const float* Ab = A + (size_t)b * astride_b;
    const int tid = threadIdx.x;
    const int tx = tid & 15, ty = tid >> 4;
    float acc[8][8] = {};

    for (int k0 = 0; k0 < K; k0 += 8) {
        if (AMODE == 0) {
            const int row = tid >> 5;
            const int col = (tid & 31) << 2;
            const float4 v = *(const float4*)(Ab + (size_t)(k0 + row) * T_SZ + tglb + col);
            *(float4*)&a_s[row][col] = v;
        } else {
            const int row  = tid >> 1;
            const int half = (tid & 1) << 2;
            const float4 v = *(const float4*)(Ab + (size_t)(tglb + row) * H_SZ + k0 + half);
            a_s[half + 0][row] = v.x; a_s[half + 1][row] = v.y;
            a_s[half + 2][row] = v.z; a_s[half + 3][row] = v.w;
        }
        {
            const int row  = tid >> 1;
            const int half = (tid & 1) << 2;
            const float4 v = *(const float4*)(W + (size_t)(r0 + row) * K + k0 + half);
            b_s[half + 0][row] = v.x; b_s[half + 1][row] = v.y;
            b_s[half + 2][row] = v.z; b_s[half + 3][row] = v.w;
        }
        __syncthreads();
        #pragma unroll
        for (int kk = 0; kk < 8; ++kk) {
            float4 a0 = *(const float4*)&a_s[kk][tx * 8];
            float4 a1 = *(const float4*)&a_s[kk][tx * 8 + 4];
            float4 w0 = *(const float4*)&b_s[kk][ty * 8];
            float4 w1 = *(const float4*)&b_s[kk][ty * 8 + 4];
            float av[8] = {a0.x, a0.y, a0.z, a0.w, a1.x, a1.y, a1.z, a1.w};
            float wv[8] = {w0.x, w0.y, w0.z, w0.w, w1.x, w1.y, w1.z, w1.w};
            #pragma unroll
            for (int i = 0; i < 8; ++i)
                #pragma unroll
                for (int j = 0; j < 8; ++j)
                    acc[i][j] += wv[i] * av[j];
        }
        __syncthreads();
    }
    float bs[8];
    #pragma unroll
    for (int i = 0; i < 8; ++i)
        bs[i] = bias1[r0 + ty * 8 + i] + bias2[r0 + ty * 8 + i];
    #pragma unroll
    for (int j = 0; j < 8; ++j) {
        float* dst = gx + ((size_t)(tloc + tx * 8 + j) * B_SZ + b) * G4H + r0 + ty * 8;
        float4 o0 = {acc[0][j] + bs[0], acc[1][j] + bs[1], acc[2][j] + bs[2], acc[3][j] + bs[3]};
        float4 o1 = {acc[4][j] + bs[4], acc[5][j] + bs[5], acc[6][j] + bs[6], acc[7][j] + bs[7]};
        *(float4*)dst = o0; *(float4*)(dst + 4) = o1;
    }
}

// ---------------------------------------------------------------------------
__global__ void wsplit(const float* __restrict__ w,
                       unsigned short* __restrict__ hi,
                       unsigned short* __restrict__ lo, int n)
{
    const int i = blockIdx.x * 256 + threadIdx.x;
    if (i < n) {
        const float v = w[i];
        const unsigned short h = f2bf_rne(v);
        hi[i] = h;
        lo[i] = f2bf_rne(v - __uint_as_float(((unsigned)h) << 16));
    }
}

// ---------------------------------------------------------------------------
// FUSED two-layer LSTM scan v13 = R14 verified structure with two serial-path
// fixes:
//  * publish window cleaned: h_out store and gx(t+1) prefetch are issued
//    AFTER the flag store (vmcnt(0) memory-clobber pins them below), so the
//    publish drain covers only the L3 hex-store ack — no HBM ops. They get a
//    full step to complete instead of stalling the flag.
//  * speculative-first consume: load exchange data ONCE before flags, check
//    exact tags; only on mismatch spin on the per-wave flags and reload the
//    mismatched values. Steady-state hit saves a full L3 round trip; misses
//    degenerate to R14's flag-first (FETCH stays bounded).
// Everything else identical to R14 (roles, rings, exact tags, prog guard,
// per-wave flags, W hi/lo AGPR-resident, h bf16, one barrier/step).
// ---------------------------------------------------------------------------
__global__ __launch_bounds__(256, 1)
void lstm_fused(const float* __restrict__ gx,                 // [tlen][B][4H]
                const unsigned short* __restrict__ w0hi,      // Whh0 [4H][H]
                const unsigned short* __restrict__ w0lo,
                const unsigned short* __restrict__ w1ahi,     // Whh1
                const unsigned short* __restrict__ w1alo,
                const unsigned short* __restrict__ w1bhi,     // Wih1
                const unsigned short* __restrict__ w1blo,
                const float* __restrict__ bih1,
                const float* __restrict__ bhh1,
                float* __restrict__ h_out,                    // [B][T][H]
                unsigned int* hex0,                           // [8][4][16][512]
                unsigned int* hex1,                           // [8][4][16][512]
                float* __restrict__ c_state,                  // [2][B][H]
                unsigned int* prog,                           // [4]
                unsigned int* flag0,                          // [4][128]
                unsigned int* flag1,                          // [4][128]
                int t0, int steps, int tlen)
{
    __shared__ __align__(16) char sH0[2][16384];  // staged h0 (both roles)
    __shared__ __align__(16) char sH1[2][16384];  // staged h1 (role 1 only)

    const int tid  = threadIdx.x;
    const int bid  = blockIdx.x;
    const int role = bid >> 7;
    const int grp  = bid & 3;             // batch group (16 batches)
    const int w    = (bid >> 2) & 31;     // unit slice (16 units)
    const int wv   = tid >> 6;            // wave 0..3
    const int lane = tid & 63;
    const int m16  = lane & 15;           // batch col / A-tile row
    const int q    = lane >> 4;           // k-subgroup / unit-in-wave
    const int ug   = w * 16 + wv * 4 + q; // this lane's unit
    const int bg   = grp * 16 + m16;      // this lane's batch
    const int swz  = (m16 & 7) << 4;

    // flags: producer wave (w,wv) -> idx w*4+wv == unit>>2; consumer thread
    // tid needs units {tid, tid+256} -> idx tid>>2 and tid>>2 + 64.
    const int fidx = tid >> 2;
    unsigned int* f0g = flag0 + grp * 128;
    unsigned int* f1g = flag1 + grp * 128;
    const int pidx = w * 4 + wv;

    // --- W fragments (AGPR-resident). A-row r=m16 <-> (gate r&3, du r>>2)
    short8 wahi[16], walo[16];            // recurrent W (Whh0 or Whh1)
    short8 wbhi[16], wblo[16];            // input W (Wih1, role 1 only)
    {
        const size_t rowbase =
            (size_t)((m16 & 3) * H_SZ + w * 16 + wv * 4 + (m16 >> 2)) * H_SZ + q * 8;
        if (role == 0) {
            #pragma unroll
            for (int kk = 0; kk < 16; ++kk) {
                wahi[kk] = *(const short8*)(w0hi + rowbase + kk * 32);
                walo[kk] = *(const short8*)(w0lo + rowbase + kk * 32);
            }
        } else {
            #pragma unroll
            for (int kk = 0; kk < 16; ++kk) {
                wahi[kk] = *(const short8*)(w1ahi + rowbase + kk * 32);
                walo[kk] = *(const short8*)(w1alo + rowbase + kk * 32);
                wbhi[kk] = *(const short8*)(w1bhi + rowbase + kk * 32);
                wblo[kk] = *(const short8*)(w1blo + rowbase + kk * 32);
            }
        }
    }

    float bsum[4] = {0.f, 0.f, 0.f, 0.f};
    if (role == 1) {
        #pragma unroll
        for (int p = 0; p < 4; ++p)
            bsum[p] = bih1[p * H_SZ + ug] + bhh1[p * H_SZ + ug];
    }

    float c_val = (t0 > 0)
        ? c_state[(size_t)role * B_SZ * H_SZ + (size_t)bg * H_SZ + ug] : 0.f;
    const float* gxp = gx + (size_t)bg * G4H + ug;
    float gxc[4] = {0.f, 0.f, 0.f, 0.f};
    unsigned prview = 0;
    if (role == 0) {
        #pragma unroll
        for (int p = 0; p < 4; ++p) gxc[p] = gxp[p * H_SZ];
        prview = AL(&prog[grp]);
    }
    long long polls = 0;

    for (int tt = 0; tt < steps; ++tt) {
        const int t  = t0 + tt;
        const int pb = tt & 1;
        char* dH0 = sH0[pb];
        char* dH1 = sH1[pb];

        // ---- acquire inputs: speculative load -> tag check -> flag-gated retry
        unsigned v0a[16], v0b[16], v1a[16], v1b[16];
        const bool have0 = (role == 1) || (t > 0);
        if (role == 0) {
            if (t > 0) {
                const unsigned tg0 = (unsigned)t;        // h0(t-1)
                const unsigned int* s0 =
                    hex0 + ((size_t)((t - 1) & 7) * 4 + grp) * 8192 + tid;
                #pragma unroll
                for (int m = 0; m < 16; ++m) {
                    v0a[m] = AL(s0 + m * 512);
                    v0b[m] = AL(s0 + m * 512 + 256);
                }
                bool ok = true;
                #pragma unroll
                for (int m = 0; m < 16; ++m)
                    ok &= ((v0a[m] & 0xFFFFu) == tg0) & ((v0b[m] & 0xFFFFu) == tg0);
                if (!ok) {
                    SPIN_GE(f0g + fidx, tg0);
                    SPIN_GE(f0g + fidx + 64, tg0);
                    for (;;) {
                        ok = true;
                        #pragma unroll
                        for (int m = 0; m < 16; ++m) {
                            if ((v0a[m] & 0xFFFFu) != tg0) { v0a[m] = AL(s0 + m * 512); ok = false; }
                            if ((v0b[m] & 0xFFFFu) != tg0) { v0b[m] = AL(s0 + m * 512 + 256); ok = false; }
                        }
                        if (ok || ++polls > POLL_BUDGET) break;
                    }
                }
            }
        } else {
            const unsigned tg0 = (unsigned)(t + 1);      // h0(t)
            const unsigned tg1 = (unsigned)t;            // h1(t-1)
            const unsigned int* s0 =
                hex0 + ((size_t)(t & 7) * 4 + grp) * 8192 + tid;
            const unsigned int* s1 =
                hex1 + ((size_t)((t - 1) & 7) * 4 + grp) * 8192 + tid;
            #pragma unroll
            for (int m = 0; m < 16; ++m) {
                v0a[m] = AL(s0 + m * 512);
                v0b[m] = AL(s0 + m * 512 + 256);
            }
            if (t > 0) {
                #pragma unroll
                for (int m = 0; m < 16; ++m) {
                    v1a[m] = AL(s1 + m * 512);
                    v1b[m] = AL(s1 + m * 512 + 256);
                }
            }
            bool ok0 = true;
            #pragma unroll
            for (int m = 0; m < 16; ++m)
                ok0 &= ((v0a[m] & 0xFFFFu) == tg0) & ((v0b[m] & 0xFFFFu) == tg0);
            if (!ok0) {
                SPIN_GE(f0g + fidx, tg0);
                SPIN_GE(f0g + fidx + 64, tg0);
                for (;;) {
                    ok0 = true;
                    #pragma unroll
                    for (int m = 0; m < 16; ++m) {
                        if ((v0a[m] & 0xFFFFu) != tg0) { v0a[m] = AL(s0 + m * 512); ok0 = false; }
                        if ((v0b[m] & 0xFFFFu) != tg0) { v0b[m] = AL(s0 + m * 512 + 256); ok0 = false; }
                    }
                    if (ok0 || ++polls > POLL_BUDGET) break;
                }
            }
            if (t > 0) {
                bool ok1 = true;
                #pragma unroll
                for (int m = 0; m < 16; ++m)
                    ok1 &= ((v1a[m] & 0xFFFFu) == tg1) & ((v1b[m] & 0xFFFFu) == tg1);
                if (!ok1) {
                    SPIN_GE(f1g + fidx, tg1);
                    SPIN_GE(f1g + fidx + 64, tg1);
                    for (;;) {
                        ok1 = true;
                        #pragma unroll
                        for (int m = 0; m < 16; ++m) {
                            if ((v1a[m] & 0xFFFFu) != tg1) { v1a[m] = AL(s1 + m * 512); ok1 = false; }
                            if ((v1b[m] & 0xFFFFu) != tg1) { v1b[m] = AL(s1 + m * 512 + 256); ok1 = false; }
                        }
                        if (ok1 || ++polls > POLL_BUDGET) break;
                    }
                }
            }
            // progress beacon: consumed h0(t) (advisory, off the latency path)
            if (w == 0 && tid == 0)
                AS(&prog[grp], (unsigned)(t + 1));
        }
        asm volatile("" ::: "memory");

        // ---- stage into swizzled LDS
        if (have0) {
            #pragma unroll
            for (int m = 0; m < 16; ++m) {
                const int oa = ((m << 10) + 2 * tid) ^ ((m & 7) << 4);
                const int ob = ((m << 10) + 2 * (tid + 256)) ^ ((m & 7) << 4);
                *(unsigned short*)(dH0 + oa) = (unsigned short)(v0a[m] >> 16);
                *(unsigned short*)(dH0 + ob) = (unsigned short)(v0b[m] >> 16);
            }
        } else {   // role 0, t == 0
            const float4 z = {0.f, 0.f, 0.f, 0.f};
            #pragma unroll
            for (int s = 0; s < 4; ++s)
                *(float4*)(dH0 + tid * 16 + s * 4096) = z;
        }
        if (role == 1) {
            if (t == 0) {
                const float4 z = {0.f, 0.f, 0.f, 0.f};
                #pragma unroll
                for (int s = 0; s < 4; ++s)
                    *(float4*)(dH1 + tid * 16 + s * 4096) = z;
            } else {
                #pragma unroll
                for (int m = 0; m < 16; ++m) {
                    const int oa = ((m << 10) + 2 * tid) ^ ((m & 7) << 4);
                    const int ob = ((m << 10) + 2 * (tid + 256)) ^ ((m & 7) << 4);
                    *(unsigned short*)(dH1 + oa) = (unsigned short)(v1a[m] >> 16);
                    *(unsigned short*)(dH1 + ob) = (unsigned short)(v1b[m] >> 16);
                }
            }
        }
        __syncthreads();   // the ONLY barrier per step

        // ---- MFMA: recurrent product (+ input product for role 1)
        f32x4 a0 = {0.f, 0.f, 0.f, 0.f};
        f32x4 a2 = {0.f, 0.f, 0.f, 0.f};
        const char* hrec = (role == 0 ? dH0 : dH1) + (m16 << 10);
        const char* hinp = dH0 + (m16 << 10);
        #pragma unroll
        for (int kk = 0; kk < 16; ++kk) {
            const int off = (kk * 64 + q * 16) ^ swz;
            const short8 hr = *(const short8*)(hrec + off);
            a0 = __builtin_amdgcn_mfma_f32_16x16x32_bf16(wahi[kk], hr, a0, 0, 0, 0);
            a2 = __builtin_amdgcn_mfma_f32_16x16x32_bf16(walo[kk], hr, a2, 0, 0, 0);
            if (role == 1) {
                const short8 h0v = *(const short8*)(hinp + off);
                a0 = __builtin_amdgcn_mfma_f32_16x16x32_bf16(wbhi[kk], h0v, a0, 0, 0, 0);
                a2 = __builtin_amdgcn_mfma_f32_16x16x32_bf16(wblo[kk], h0v, a2, 0, 0, 0);
            }
        }

        // ---- update + publish (clean vmcnt window) + flag, THEN HBM ops
        {
            const float base0 = (role == 0) ? gxc[0] : bsum[0];
            const float base1 = (role == 0) ? gxc[1] : bsum[1];
            const float base2 = (role == 0) ? gxc[2] : bsum[2];
            const float base3 = (role == 0) ? gxc[3] : bsum[3];
            const float si = sigmoid_f(a0[0] + a2[0] + base0);
            const float sf = sigmoid_f(a0[1] + a2[1] + base1);
            const float tc = tanh_f(a0[2] + a2[2] + base2);
            const float so = sigmoid_f(a0[3] + a2[3] + base3);
            c_val = sf * c_val + si * tc;
            const float h = so * tanh_f(c_val);
            const unsigned val = (((unsigned)f2bf_rne(h)) << 16) | (unsigned)(t + 1);
            if (role == 0) {
                // h0-ring overwrite guard: layer 1 must have consumed h0(t-8)
                while ((int)prview < t - 6) {
                    if (++polls > POLL_BUDGET) break;
                    prview = AL(&prog[grp]);
                }
                AS(hex0 + ((size_t)(t & 7) * 4 + grp) * 8192 + m16 * 512 + ug, val);
                asm volatile("s_waitcnt vmcnt(0)" ::: "memory");
                if (lane == 0) AS(f0g + pidx, (unsigned)(t + 1));
            } else {
                AS(hex1 + ((size_t)(t & 7) * 4 + grp) * 8192 + m16 * 512 + ug, val);
                asm volatile("s_waitcnt vmcnt(0)" ::: "memory");
                if (lane == 0) AS(f1g + pidx, (unsigned)(t + 1));
                // HBM store AFTER the flag: a full step to complete
                h_out[((size_t)bg * T_SZ + t) * H_SZ + ug] = h;
            }
        }
        // ---- tail prefetches (pinned below the vmcnt by its memory clobber)
        if (role == 0) {
            if (tt + 1 < steps) {
                const float* gn = gxp + (size_t)(tt + 1) * (B_SZ * G4H);
                #pragma unroll
                for (int p = 0; p < 4; ++p) gxc[p] = gn[p * H_SZ];
            }
            prview = AL(&prog[grp]);
        }
    }
    // cross-chunk c carry
    if (t0 + steps < T_SZ)
        c_state[(size_t)role * B_SZ * H_SZ + (size_t)bg * H_SZ + ug] = c_val;
}

// Beacon: surfaces ws_size (MiB) through the absmax error if ws is too small.
__global__ void debug_ws_beacon(float* out, float v)
{
    if (threadIdx.x == 0 && blockIdx.x == 0) out[0] = v;
}

// ---------------------------------------------------------------------------
extern "C" void kernel_launch(void* const* d_in, const int* in_sizes, int n_in,
                              void* d_out, int out_size, void* d_ws, size_t ws_size,
                              hipStream_t stream)
{
    const float* x    = (const float*)d_in[0];
    const float* Wih0 = (const float*)d_in[1];
    const float* Whh0 = (const float*)d_in[2];
    const float* bih0 = (const float*)d_in[3];
    const float* bhh0 = (const float*)d_in[4];
    const float* Wih1 = (const float*)d_in[5];
    const float* Whh1 = (const float*)d_in[6];
    const float* bih1 = (const float*)d_in[7];
    const float* bhh1 = (const float*)d_in[8];
    float* out = (float*)d_out;

    const size_t ringB = (size_t)8 * 4 * 16 * H_SZ * 4;   // 1 MiB per ring
    const size_t cstB  = (size_t)2 * B_SZ * H_SZ * 4;     // 256 KiB
    const size_t prgB  = 8192;                            // prog + flags
    const size_t wB    = (size_t)G4H * H_SZ * 2;          // 2 MiB per matrix
    const size_t fixed = 2 * ringB + cstB + prgB + 6 * wB;

    static const int opts[] = {1536, 768, 512, 384, 256, 128};
    int T_CHUNK = 0;
    for (int i = 0; i < 6; ++i) {
        const size_t need = (size_t)B_SZ * G4H * opts[i] * 4 + fixed;
        if (need <= ws_size) { T_CHUNK = opts[i]; break; }
    }
    if (T_CHUNK == 0) {
        debug_ws_beacon<<<1, 1, 0, stream>>>(out, (float)(ws_size >> 20));
        return;
    }

    char* ws = (char*)d_ws;
    const size_t gxB = (size_t)B_SZ * G4H * T_CHUNK * 4;
    float*          gx      = (float*)ws;
    unsigned int*   hex0    = (unsigned int*)(ws + gxB);
    unsigned int*   hex1    = (unsigned int*)(ws + gxB + ringB);
    float*          c_state = (float*)(ws + gxB + 2 * ringB);
    unsigned int*   prog    = (unsigned int*)(ws + gxB + 2 * ringB + cstB);
    unsigned int*   flag0   = prog + 64;                  // [4][128]
    unsigned int*   flag1   = flag0 + 512;                // [4][128]
    unsigned short* w0hi    = (unsigned short*)(ws + gxB + 2 * ringB + cstB + prgB);
    unsigned short* w0lo    = w0hi  + G4H * H_SZ;
    unsigned short* w1ahi   = w0lo  + G4H * H_SZ;
    unsigned short* w1alo   = w1ahi + G4H * H_SZ;
    unsigned short* w1bhi   = w1alo + G4H * H_SZ;
    unsigned short* w1blo   = w1bhi + G4H * H_SZ;

    const int nW = G4H * H_SZ;
    wsplit<<<(nW + 255) / 256, 256, 0, stream>>>(Whh0, w0hi, w0lo, nW);
    wsplit<<<(nW + 255) / 256, 256, 0, stream>>>(Whh1, w1ahi, w1alo, nW);
    wsplit<<<(nW + 255) / 256, 256, 0, stream>>>(Wih1, w1bhi, w1blo, nW);

    // fresh tags + flags each call (replay safety: tag/flag 0 never valid)
    hipMemsetAsync(hex0, 0, 2 * ringB, stream);
    hipMemsetAsync(prog, 0, prgB, stream);

    const dim3 ggrid(T_CHUNK / 128, G4H / 128, B_SZ);
    for (int t0 = 0; t0 < T_SZ; t0 += T_CHUNK) {
        gemm_gx<0><<<ggrid, 256, 0, stream>>>(x, Wih0, bih0, bhh0, gx, C_SZ,
                                              C_SZ * T_SZ, t0, T_CHUNK);
        lstm_fused<<<256, 256, 0, stream>>>(gx, w0hi, w0lo, w1ahi, w1alo,
                                            w1bhi, w1blo, bih1, bhh1, out,
                                            hex0, hex1, c_state, prog,
                                            flag0, flag1, t0, T_CHUNK, T_CHUNK);
    }
}